// Round 9
// baseline (859.241 us; speedup 1.0000x reference)
//
#include <hip/hip_runtime.h>

// ---- problem dims (fixed by reference) ----
#define V_ 30000
#define D_ 300
#define DP_ 320
#define T_ 24
#define H_ 256
#define NT_ 6000
#define NU_ 4000
#define N_ 10000
#define F_ 512
#define Z_ 256
#define E_ 80000
#define B_ 2000
#define H1_ 64
#define H2_ 100
#define HEADS_ 8
#define E2_ (E_ + N_)

typedef __bf16 bf16_t;
typedef bf16_t bf16x8 __attribute__((ext_vector_type(8)));
typedef float  f32x4  __attribute__((ext_vector_type(4)));

// async global->LDS, 16B per lane; lds dest = base + lane*16 (wave-uniform base)
__device__ __forceinline__ void gll16(const bf16_t* g, bf16_t* l)
{
    __builtin_amdgcn_global_load_lds(
        (const __attribute__((address_space(1))) void*)g,
        (__attribute__((address_space(3))) void*)l, 16, 0, 0);
}

// =======================================================================
// 128x128 MFMA GEMM: C = A[M,K] @ B[N,K]^T (+bias).  (R14 2-buffer loop)
// =======================================================================
struct GCfg {
    const bf16_t* A; const bf16_t* B; const float* bias;
    float* Cf; bf16_t* Cb; int M, N, K, ldc;
    const int* gtok; int t0;
};

template<bool OUTBF>
__global__ __launch_bounds__(256) void mfma_gemm(GCfg g0, GCfg g1)
{
    const GCfg g = blockIdx.z ? g1 : g0;
    __shared__ __align__(16) bf16_t SMEM[16384];   // 32 KB
    const int tid  = (int)threadIdx.x;
    const int wave = tid >> 6, lane = tid & 63;
    const int quad = lane >> 4, l16 = lane & 15;
    const int mq = (wave & 1) * 64, nq = (wave >> 1) * 64;

    int bx = (int)blockIdx.x, by = (int)blockIdx.y;
    {
        int gx = (int)gridDim.x, total = gx * (int)gridDim.y;
        if ((total & 7) == 0) {
            int L = by * gx + bx;
            int F = (L & 7) * (total >> 3) + (L >> 3);
            bx = F % gx;
            by = F / gx;
        }
    }
    const int mbase = by * 128, nbase = bx * 128;
    const int M = g.M, N = g.N, K = g.K, ldc = g.ldc;

    const bf16_t* agp[2];
    const bf16_t* bgp[2];
#pragma unroll
    for (int j = 0; j < 2; j++) {
        int i = wave * 128 + j * 64 + lane;
        int c = i >> 7, row = i & 127;
        int r = mbase + row; if (r >= M) r = M - 1;
        int src = g.gtok ? g.gtok[(r % NT_) * T_ + g.t0 + (r / NT_)] : r;
        agp[j] = g.A + (size_t)src * K + c * 8;
        int rb = nbase + row; if (rb >= N) rb = N - 1;
        bgp[j] = g.B + (size_t)rb * K + c * 8;
    }

    f32x4 acc[4][4];
#pragma unroll
    for (int mi = 0; mi < 4; mi++)
#pragma unroll
        for (int ni = 0; ni < 4; ni++) acc[mi][ni] = (f32x4){0.f, 0.f, 0.f, 0.f};

    auto stage = [&](int b, int k0) {
        bf16_t* ab = SMEM + b * 4096 + wave * 1024;
        bf16_t* bb = SMEM + 8192 + b * 4096 + wave * 1024;
        gll16(agp[0] + k0, ab);
        gll16(agp[1] + k0, ab + 512);
        gll16(bgp[0] + k0, bb);
        gll16(bgp[1] + k0, bb + 512);
    };

    const int niter = K >> 5;
    stage(0, 0);
    for (int ks = 0; ks < niter; ks++) {
        __syncthreads();
        if (ks + 1 < niter) stage((ks + 1) & 1, (ks + 1) * 32);
        const bf16_t* Ab = SMEM + (ks & 1) * 4096;
        const bf16_t* Bb = SMEM + 8192 + (ks & 1) * 4096;
        bf16x8 afr[4], bfr[4];
#pragma unroll
        for (int mi = 0; mi < 4; mi++)
            afr[mi] = *(const bf16x8*)(Ab + (size_t)(quad * 128 + mq + mi * 16 + l16) * 8);
#pragma unroll
        for (int ni = 0; ni < 4; ni++)
            bfr[ni] = *(const bf16x8*)(Bb + (size_t)(quad * 128 + nq + ni * 16 + l16) * 8);
#pragma unroll
        for (int mi = 0; mi < 4; mi++)
#pragma unroll
            for (int ni = 0; ni < 4; ni++)
                acc[mi][ni] = __builtin_amdgcn_mfma_f32_16x16x32_bf16(
                    afr[mi], bfr[ni], acc[mi][ni], 0, 0, 0);
    }

    if (OUTBF) {
        __syncthreads();
#pragma unroll
        for (int ni = 0; ni < 4; ni++) {
            int colc = nq + ni * 16 + l16;
            float bv = g.bias ? g.bias[nbase + colc] : 0.f;
            int cc = colc >> 3, off = colc & 7;
#pragma unroll
            for (int mi = 0; mi < 4; mi++)
#pragma unroll
                for (int r = 0; r < 4; r++) {
                    int row = mq + mi * 16 + quad * 4 + r;
                    int sw = (row ^ (row >> 3)) & 7;
                    SMEM[row * 128 + ((cc ^ sw) << 3) + off] =
                        (bf16_t)(acc[mi][ni][r] + bv);
                }
        }
        __syncthreads();
        {
            int row = tid >> 1, seg = tid & 1;
            int sw = (row ^ (row >> 3)) & 7;
            int growr = mbase + row;
            if (growr < M) {
#pragma unroll
                for (int q = 0; q < 8; q++) {
                    int cc = seg * 8 + q;
                    bf16x8 v = *(const bf16x8*)(SMEM + row * 128 + ((cc ^ sw) << 3));
                    *(bf16x8*)(g.Cb + (size_t)growr * ldc + nbase + cc * 8) = v;
                }
            }
        }
    } else {
#pragma unroll
        for (int ni = 0; ni < 4; ni++) {
            int col = nbase + nq + ni * 16 + l16;
            if (col >= N) continue;
            float bv = g.bias ? g.bias[col] : 0.f;
#pragma unroll
            for (int mi = 0; mi < 4; mi++)
#pragma unroll
                for (int r = 0; r < 4; r++) {
                    int row = mbase + mq + mi * 16 + quad * 4 + r;
                    if (row >= M) continue;
                    g.Cf[(size_t)row * ldc + col] = acc[mi][ni][r] + bv;
                }
        }
    }
}

// =======================================================================
// R18: gru_mega at 1024 threads / 16 waves (TLP fix).
// R17 post-mortem: ping-pong was null (453->445us). Counters showed no
// saturated pipe (MFMA 24%, VALU 29%, L2 45%, HBM 1.5%) at occupancy
// 17% = 2 waves/SIMD: the serial 6-phase/5-barrier chain per step had
// nothing to interleave with. Grid is fixed at 188 blocks (32 rows each),
// so the only TLP lever is block size: 16 waves x 16 cols/wave doubles
// waves/SIMD to 4. Per-wave state halves (acc 32 f32, ping-pong 24,
// ~95 VGPR < 128 cap), traffic and layouts unchanged.
// =======================================================================
struct MegaLay {
    const bf16_t* temb;    // [V][320] bf16 (cols 300.. zero-padded)
    const int*    gnf;     // [NT][24]
    const bf16_t* wih0;    // frag-major, nks=10
    const bf16_t* whh0;    // frag-major, nks=8
    const bf16_t* wih1;    // frag-major, nks=8
    const bf16_t* whh1;    // frag-major, nks=8
    const float *bih0, *bhh0, *bih1, *bhh1;
    const bf16_t* h0in;    // [NT][256]
    const bf16_t* h1in;
    bf16_t*       h1out;   // final h1
};

__device__ __forceinline__ float rcp_(float x)
{
    float r;
    asm("v_rcp_f32 %0, %1" : "=v"(r) : "v"(x));
    return r;
}
__device__ __forceinline__ float sigm_(float x)
{
    return rcp_(1.f + __expf(-x));
}
__device__ __forceinline__ float tanh_(float x)
{
    x = fminf(fmaxf(x, -15.f), 15.f);
    float t = __expf(2.f * x);
    return 1.f - 2.f * rcp_(t + 1.f);
}

// swizzled LDS addr for h tile [32 rows][512B]: XOR row into byte bits 4-6
#define HSW(Hb, row, byte) ((char*)(Hb) + ((((row) * 512) + (byte)) ^ (((row) & 7) << 4)))

__global__ __launch_bounds__(1024, 4) void gru_mega(MegaLay L)
{
    __shared__ __align__(16) bf16_t H0L[8192];    // 16 KB h0[32][256] swizzled
    __shared__ __align__(16) bf16_t H1L[8192];    // 16 KB h1[32][256] swizzled
    __shared__ __align__(16) bf16_t XE[20480];    // 40 KB 2x xe[32][320] chunk-swz
    __shared__ int TOK[768];                      // 3 KB  tokens [32][24]
    const int tid  = (int)threadIdx.x;
    const int wv   = tid >> 6, lane = tid & 63;   // wv 0..15
    const int quad = lane >> 4, l16 = lane & 15;
    const int row0 = (int)blockIdx.x * 32;

    // ---- tokens + initial h into swizzled LDS ----
    if (tid < 768) {
        int gi = row0 * T_ + tid; if (gi >= NT_ * T_) gi = NT_ * T_ - 1;
        TOK[tid] = L.gnf[gi];
    }
    {
        int rowl = tid >> 5, seg = tid & 31;
        int grow = row0 + rowl; if (grow >= NT_) grow = NT_ - 1;
        *(bf16x8*)HSW(H0L, rowl, seg * 16) =
            *(const bf16x8*)(L.h0in + (size_t)grow * H_ + seg * 8);
        *(bf16x8*)HSW(H1L, rowl, seg * 16) =
            *(const bf16x8*)(L.h1in + (size_t)grow * H_ + seg * 8);
    }

    // per-lane biases for this wave's 16-col slice: r,z combined; n split
    float brz0[2], bni0, bnh0, brz1[2], bni1, bnh1;
    {
        int col = wv * 16 + l16;
        brz0[0] = L.bih0[col] + L.bhh0[col];
        brz0[1] = L.bih0[256 + col] + L.bhh0[256 + col];
        bni0    = L.bih0[512 + col];
        bnh0    = L.bhh0[512 + col];
        brz1[0] = L.bih1[col] + L.bhh1[col];
        brz1[1] = L.bih1[256 + col] + L.bhh1[256 + col];
        bni1    = L.bih1[512 + col];
        bnh1    = L.bhh1[512 + col];
    }

    // xe gather: 20 gll16 cover 32 rows x 40 chunks(16B); chunk slot s of
    // row holds global chunk s^(row&7) (pre-swizzled source, linear dest).
    auto gather = [&](int t) {
        bf16_t* xb = XE + (t & 1) * 10240;
#pragma unroll
        for (int k = 0; k < 2; k++) {
            int i = wv + k * 16;
            if (i < 20) {
                int flat = i * 64 + lane;
                int row  = flat / 40;
                int s    = flat - row * 40;
                int c4   = s ^ (row & 7);
                int tok  = TOK[row * T_ + t];
                gll16(L.temb + (size_t)tok * DP_ + c4 * 8, xb + i * 512 + lane * 8);
            }
        }
    };

    // generic K-loop, B-frags ping-ponged in regs (named arrays, rule #20).
    auto run_gemm = [&](auto&& loadA, const bf16_t* W, int nks,
                        f32x4 (&arz)[2][2], f32x4 (&an)[2]) {
        bf16x8 bA[3], bB[3];
        auto loadB = [&](bf16x8 (&b)[3], int ks) {
#pragma unroll
            for (int g = 0; g < 3; g++)
                b[g] = *(const bf16x8*)(W +
                    (((size_t)(g * 16 + wv) * nks + ks) << 9) + lane * 8);
        };
        auto mstep = [&](bf16x8 (&b)[3], int ks) {
            bf16x8 afr[2];
            loadA(afr, ks);
#pragma unroll
            for (int m = 0; m < 2; m++) {
                arz[m][0] = __builtin_amdgcn_mfma_f32_16x16x32_bf16(
                    afr[m], b[0], arz[m][0], 0, 0, 0);
                arz[m][1] = __builtin_amdgcn_mfma_f32_16x16x32_bf16(
                    afr[m], b[1], arz[m][1], 0, 0, 0);
                an[m] = __builtin_amdgcn_mfma_f32_16x16x32_bf16(
                    afr[m], b[2], an[m], 0, 0, 0);
            }
        };
        loadB(bA, 0);
#pragma unroll 1
        for (int kp = 0; kp < nks; kp += 2) {
            loadB(bB, kp + 1);               // nks even: kp+1 always valid
            mstep(bA, kp);
            if (kp + 2 < nks) loadB(bA, kp + 2);
            mstep(bB, kp + 1);
        }
    };

    __syncthreads();          // TOK + h visible
    gather(0);                // prologue prefetch

    for (int t = 0; t < T_; t++) {
        __syncthreads();      // implicit vmcnt(0): xe(t) landed & visible
        if (t + 1 < T_) gather(t + 1);

        f32x4 arz[2][2], an_i[2], an_h[2];
#pragma unroll
        for (int m = 0; m < 2; m++) {
            arz[m][0] = (f32x4){0.f, 0.f, 0.f, 0.f};
            arz[m][1] = (f32x4){0.f, 0.f, 0.f, 0.f};
            an_i[m]   = (f32x4){0.f, 0.f, 0.f, 0.f};
            an_h[m]   = (f32x4){0.f, 0.f, 0.f, 0.f};
        }

        // ---- layer 0: Gi0 (xe) + Gh0 (h0) ----
        {
            const bf16_t* xb = XE + (t & 1) * 10240;
            run_gemm([&](bf16x8* afr, int ks) {
#pragma unroll
                for (int m = 0; m < 2; m++) {
                    int row = m * 16 + l16;
                    afr[m] = *(const bf16x8*)(xb + row * DP_ +
                               (((ks * 4 + quad) ^ (row & 7)) << 3));
                }
            }, L.wih0, 10, arz, an_i);
            run_gemm([&](bf16x8* afr, int ks) {
#pragma unroll
                for (int m = 0; m < 2; m++)
                    afr[m] = *(const bf16x8*)HSW(H0L, m * 16 + l16,
                                                 ks * 64 + quad * 16);
            }, L.whh0, 8, arz, an_h);
        }
        __syncthreads();      // all h0 reads done

        // ---- gates L0 -> h0 in place ----
#pragma unroll
        for (int m = 0; m < 2; m++) {
            int col = wv * 16 + l16;
#pragma unroll
            for (int r = 0; r < 4; r++) {
                int rowl = m * 16 + quad * 4 + r;
                float hold = (float)*(const bf16_t*)HSW(H0L, rowl, col * 2);
                float rg = sigm_(arz[m][0][r] + brz0[0]);
                float zg = sigm_(arz[m][1][r] + brz0[1]);
                float ng = tanh_(an_i[m][r] + bni0 + rg * (an_h[m][r] + bnh0));
                *(bf16_t*)HSW(H0L, rowl, col * 2) =
                    (bf16_t)((1.f - zg) * ng + zg * hold);
            }
        }
        __syncthreads();      // new h0 visible

        // ---- layer 1: Gi1 (h0 new) + Gh1 (h1) ----
#pragma unroll
        for (int m = 0; m < 2; m++) {
            arz[m][0] = (f32x4){0.f, 0.f, 0.f, 0.f};
            arz[m][1] = (f32x4){0.f, 0.f, 0.f, 0.f};
            an_i[m]   = (f32x4){0.f, 0.f, 0.f, 0.f};
            an_h[m]   = (f32x4){0.f, 0.f, 0.f, 0.f};
        }
        run_gemm([&](bf16x8* afr, int ks) {
#pragma unroll
            for (int m = 0; m < 2; m++)
                afr[m] = *(const bf16x8*)HSW(H0L, m * 16 + l16,
                                             ks * 64 + quad * 16);
        }, L.wih1, 8, arz, an_i);
        run_gemm([&](bf16x8* afr, int ks) {
#pragma unroll
            for (int m = 0; m < 2; m++)
                afr[m] = *(const bf16x8*)HSW(H1L, m * 16 + l16,
                                             ks * 64 + quad * 16);
        }, L.whh1, 8, arz, an_h);
        __syncthreads();      // all h1 reads done

        // ---- gates L1 -> h1 in place ----
#pragma unroll
        for (int m = 0; m < 2; m++) {
            int col = wv * 16 + l16;
#pragma unroll
            for (int r = 0; r < 4; r++) {
                int rowl = m * 16 + quad * 4 + r;
                float hold = (float)*(const bf16_t*)HSW(H1L, rowl, col * 2);
                float rg = sigm_(arz[m][0][r] + brz1[0]);
                float zg = sigm_(arz[m][1][r] + brz1[1]);
                float ng = tanh_(an_i[m][r] + bni1 + rg * (an_h[m][r] + bnh1));
                *(bf16_t*)HSW(H1L, rowl, col * 2) =
                    (bf16_t)((1.f - zg) * ng + zg * hold);
            }
        }
        // next iteration's top __syncthreads separates these writes from
        // the next step's H1L reads.
    }

    __syncthreads();
    {
        int rowl = tid >> 5, seg = tid & 31;
        int grow = row0 + rowl;
        if (grow < NT_) {
            bf16x8 v = *(const bf16x8*)HSW(H1L, rowl, seg * 16);
            *(bf16x8*)(L.h1out + (size_t)grow * H_ + seg * 8) = v;
        }
    }
}

// ---------------- prep: all f32->bf16 conversions in one launch ----------------
// transp: 0 = row-major (pad cols), 1 = transpose, 2 = fragment-major
//         (nks = cout/32; cin = src inner dim, zero-pad kk >= cin)
struct SegD { const float* src; bf16_t* dst; int rows, cin, cout, transp; };
struct PrepArgs { SegD seg[11]; long long base[12]; int nseg; long long total; };

__global__ void prep_kern(PrepArgs pa)
{
    long long stride = (long long)gridDim.x * blockDim.x;
    for (long long i = (long long)blockIdx.x * blockDim.x + threadIdx.x;
         i < pa.total; i += stride) {
        int k = 0;
        while (k + 1 < pa.nseg && i >= pa.base[k + 1]) k++;
        long long local = i - pa.base[k];
        SegD sg = pa.seg[k];
        float v;
        if (sg.transp == 2) {
            int nks  = sg.cout >> 5;
            int o    = (int)local;
            int e    = o & 7;
            int lane = (o >> 3) & 63;
            int rest = o >> 9;
            int ks   = rest % nks;
            int gcb  = rest / nks;
            int r    = (gcb >> 4) * 256 + (gcb & 15) * 16 + (lane & 15);
            int kk   = ks * 32 + (lane >> 4) * 8 + e;
            v = (kk < sg.cin) ? sg.src[(size_t)r * sg.cin + kk] : 0.f;
        } else {
            int r = (int)(local / sg.cout);
            int c = (int)(local - (long long)r * sg.cout);
            if (sg.transp) v = sg.src[(size_t)c * sg.rows + r];
            else           v = (c < sg.cin) ? sg.src[(size_t)r * sg.cin + c] : 0.f;
        }
        sg.dst[local] = (bf16_t)v;
    }
}

// ---------------- fused init ----------------
__global__ void init_all(const float* __restrict__ h0in, bf16_t* __restrict__ h0b,
                         bf16_t* __restrict__ h1b,
                         int* __restrict__ deg, int* __restrict__ dcnt,
                         float* __restrict__ loss2, float* __restrict__ b_ml,
                         const float* __restrict__ b_mu, const float* __restrict__ b_lv)
{
    int i = blockIdx.x * blockDim.x + threadIdx.x;
    if (i < NT_ * H_) {
        h0b[i] = (bf16_t)h0in[i];
        h1b[i] = (bf16_t)h0in[NT_ * H_ + i];
    }
    if (i < N_) { deg[i] = 0; dcnt[i] = 0; }
    if (i < 2 * Z_) b_ml[i] = (i < Z_) ? b_mu[i] : b_lv[i - Z_];
    if (i < 2) loss2[i] = 0.f;
}

// ---------------- CSR build (by dst, self-loops appended) ----------------
__device__ __forceinline__ void edge_sd(const int* __restrict__ ei, int e, int& s, int& d)
{
    if (e < E_) { s = ei[e]; d = ei[E_ + e]; }
    else        { s = d = e - E_; }
}

__global__ void csr_hist(const int* __restrict__ ei, int* __restrict__ deg)
{
    int e = blockIdx.x * blockDim.x + threadIdx.x;
    if (e >= E2_) return;
    int s, d; edge_sd(ei, e, s, d);
    atomicAdd(deg + d, 1);
}

__global__ void csr_scan(const int* __restrict__ deg, int* __restrict__ rowptr)
{
    __shared__ int buf[256];
    __shared__ int carry;
    int tid = (int)threadIdx.x;
    if (tid == 0) { carry = 0; rowptr[0] = 0; }
    __syncthreads();
    for (int c0 = 0; c0 < N_; c0 += 256) {
        int i = c0 + tid;
        buf[tid] = (i < N_) ? deg[i] : 0;
        __syncthreads();
        for (int off = 1; off < 256; off <<= 1) {
            int t = (tid >= off) ? buf[tid - off] : 0;
            __syncthreads();
            buf[tid] += t;
            __syncthreads();
        }
        if (i < N_) rowptr[i + 1] = carry + buf[tid];
        __syncthreads();
        if (tid == 255) carry += buf[255];
        __syncthreads();
    }
}

__global__ void csr_scatter(const int* __restrict__ ei, const int* __restrict__ rowptr,
                            int* __restrict__ dcnt, int* __restrict__ csrc)
{
    int e = blockIdx.x * blockDim.x + threadIdx.x;
    if (e >= E2_) return;
    int s, d; edge_sd(ei, e, s, d);
    int pos = rowptr[d] + atomicAdd(dcnt + d, 1);
    csrc[pos] = s;
}

// ---------------- VAE (grid-stride; 256 atomics) ----------------
__global__ __launch_bounds__(256) void vae_z_kl(
    const float* __restrict__ ml, const float* __restrict__ eps,
    bf16_t* __restrict__ z_out, float* __restrict__ kl_out)
{
    float t = 0.f;
    int stride = (int)gridDim.x * 256;
    for (int idx = blockIdx.x * 256 + threadIdx.x; idx < NU_ * Z_; idx += stride) {
        int row = idx >> 8, c = idx & 255;
        float m = ml[(size_t)row * 512 + c];
        float l = ml[(size_t)row * 512 + 256 + c];
        float el = expf(l);
        z_out[idx] = (bf16_t)(m + expf(0.5f * l) * eps[idx]);
        t += -0.5f * (1.f + l - m * m - el);
    }
    __shared__ float red[256];
    red[threadIdx.x] = t;
    __syncthreads();
    for (int s = 128; s > 0; s >>= 1) {
        if ((int)threadIdx.x < s) red[threadIdx.x] += red[threadIdx.x + s];
        __syncthreads();
    }
    if (threadIdx.x == 0) atomicAdd(kl_out, red[0] * (1.f / NU_));
}

__global__ __launch_bounds__(256) void rec_loss_kern(
    const float* __restrict__ rec, const float* __restrict__ uf,
    float* __restrict__ loss_out)
{
    float t = 0.f;
    int stride = (int)gridDim.x * 256;
    for (int idx = blockIdx.x * 256 + threadIdx.x; idx < NU_ * F_; idx += stride) {
        float d = rec[idx] - uf[idx];
        t += d * d;
    }
    __shared__ float red[256];
    red[threadIdx.x] = t;
    __syncthreads();
    for (int s = 128; s > 0; s >>= 1) {
        if ((int)threadIdx.x < s) red[threadIdx.x] += red[threadIdx.x + s];
        __syncthreads();
    }
    if (threadIdx.x == 0) atomicAdd(loss_out, red[0] * (1.f / (NU_ * F_)));
}

// ---------------- assemble x_in = [hn[:B], z, hn[B:]] (bf16 -> bf16) ----------------
__global__ void assemble_xin(const bf16_t* __restrict__ h1, bf16_t* __restrict__ x_in)
{
    int idx = blockIdx.x * blockDim.x + threadIdx.x;
    if (idx >= NT_ * H_) return;
    int row = idx >> 8, col = idx & 255;
    int dst = (row < B_) ? row : (row + NU_);
    x_in[(size_t)dst * H_ + col] = h1[idx];
}

// ---------------- GAT ----------------
__global__ void gat_attn_coef_bf(const bf16_t* __restrict__ xp,
                                 const float* __restrict__ a_src,
                                 const float* __restrict__ a_dst,
                                 float* __restrict__ asn, float* __restrict__ adn,
                                 int heads, int C)
{
    int i = blockIdx.x * blockDim.x + threadIdx.x;
    if (i >= N_ * heads) return;
    int node = i / heads, h = i - node * heads;
    const bf16_t* x = xp + (size_t)(node * heads + h) * C;
    float s = 0.f, d = 0.f;
    for (int c8 = 0; c8 < C; c8 += 8) {
        bf16x8 v = *(const bf16x8*)(x + c8);
#pragma unroll
        for (int j = 0; j < 8; j++) {
            float vv = (float)v[j];
            s += vv * a_src[h * C + c8 + j];
            d += vv * a_dst[h * C + c8 + j];
        }
    }
    asn[i] = s;
    adn[i] = d;
}

__global__ void gat_attn_coef(const float* __restrict__ xp, const float* __restrict__ a_src,
                              const float* __restrict__ a_dst, float* __restrict__ asn,
                              float* __restrict__ adn, int heads, int C)
{
    int i = blockIdx.x * blockDim.x + threadIdx.x;
    if (i >= N_ * heads) return;
    int node = i / heads, h = i - node * heads;
    const float* x = xp + (size_t)(node * heads + h) * C;
    float s = 0.f, d = 0.f;
    for (int c = 0; c < C; c++) {
        float v = x[c];
        s += v * a_src[h * C + c];
        d += v * a_dst[h * C + c];
    }
    asn[i] = s;
    adn[i] = d;
}

// fused edge-softmax + aggregate, layer 1: BLOCK per dst, all 8 heads.
__global__ __launch_bounds__(256) void gat_agg1(
    const int* __restrict__ rowptr, const int* __restrict__ csrc,
    const float* __restrict__ asn, const float* __restrict__ adn,
    const bf16_t* __restrict__ xp, const float* __restrict__ bias,
    bf16_t* __restrict__ x1out)
{
    int d = blockIdx.x;
    int tid = (int)threadIdx.x;
    int beg = rowptr[d], end = rowptr[d + 1];
    int h0 = tid >> 6, h1 = h0 + 4;
    float ad0 = adn[d * 8 + h0], ad1 = adn[d * 8 + h1];
    float mx0 = -1e30f, mx1 = -1e30f;
    for (int e = beg; e < end; e++) {
        int s = csrc[e];
        float l0 = asn[s * 8 + h0] + ad0; l0 = (l0 > 0.f) ? l0 : 0.2f * l0;
        float l1 = asn[s * 8 + h1] + ad1; l1 = (l1 > 0.f) ? l1 : 0.2f * l1;
        mx0 = fmaxf(mx0, l0); mx1 = fmaxf(mx1, l1);
    }
    float den0 = 0.f, den1 = 0.f, acc0 = 0.f, acc1 = 0.f;
    for (int e = beg; e < end; e++) {
        int s = csrc[e];
        float l0 = asn[s * 8 + h0] + ad0; l0 = (l0 > 0.f) ? l0 : 0.2f * l0;
        float l1 = asn[s * 8 + h1] + ad1; l1 = (l1 > 0.f) ? l1 : 0.2f * l1;
        float p0 = expf(l0 - mx0), p1 = expf(l1 - mx1);
        den0 += p0; den1 += p1;
        acc0 += p0 * (float)xp[(size_t)s * 512 + tid];
        acc1 += p1 * (float)xp[(size_t)s * 512 + 256 + tid];
    }
    x1out[(size_t)d * 512 + tid]       = (bf16_t)(bias[tid] + acc0 / den0);
    x1out[(size_t)d * 512 + 256 + tid] = (bf16_t)(bias[256 + tid] + acc1 / den1);
}

// fused edge-softmax + aggregate, layer 2 (1 head x 100ch): wave per dst
__global__ __launch_bounds__(256) void gat_agg2(
    const int* __restrict__ rowptr, const int* __restrict__ csrc,
    const float* __restrict__ asn, const float* __restrict__ adn,
    const float* __restrict__ xp, const float* __restrict__ bias,
    float* __restrict__ outp)
{
    int d = blockIdx.x * 4 + ((int)threadIdx.x >> 6);
    if (d >= N_) return;
    int lane = (int)threadIdx.x & 63;
    int beg = rowptr[d], end = rowptr[d + 1];
    float adnd = adn[d];
    float mx = -1e30f;
    for (int e = beg; e < end; e++) {
        float l = asn[csrc[e]] + adnd;
        l = (l > 0.f) ? l : 0.2f * l;
        mx = fmaxf(mx, l);
    }
    float den = 0.f, acc0 = 0.f, acc1 = 0.f;
    for (int e = beg; e < end; e++) {
        int s = csrc[e];
        float l = asn[s] + adnd;
        l = (l > 0.f) ? l : 0.2f * l;
        float p = expf(l - mx);
        den += p;
        acc0 += p * xp[(size_t)s * H2_ + lane];
        if (lane < H2_ - 64) acc1 += p * xp[(size_t)s * H2_ + 64 + lane];
    }
    outp[(size_t)d * H2_ + lane] = bias[lane] + acc0 / den;
    if (lane < H2_ - 64)
        outp[(size_t)d * H2_ + 64 + lane] = bias[64 + lane] + acc1 / den;
}

// ---------------- launcher ----------------
extern "C" void kernel_launch(void* const* d_in, const int* in_sizes, int n_in,
                              void* d_out, int out_size, void* d_ws, size_t ws_size,
                              hipStream_t stream)
{
    const float* user_feats = (const float*)d_in[1];
    const int*   gnf        = (const int*)d_in[2];
    const int*   ei         = (const int*)d_in[3];
    const float* temb       = (const float*)d_in[4];
    const float* w_ih0      = (const float*)d_in[5];
    const float* w_hh0      = (const float*)d_in[6];
    const float* b_ih0      = (const float*)d_in[7];
    const float* b_hh0      = (const float*)d_in[8];
    const float* w_ih1      = (const float*)d_in[9];
    const float* w_hh1      = (const float*)d_in[10];
    const float* b_ih1      = (const float*)d_in[11];
    const float* b_hh1      = (const float*)d_in[12];
    const float* h0in       = (const float*)d_in[13];
    const float* w_mu       = (const float*)d_in[14];
    const float* b_mu       = (const float*)d_in[15];
    const float* w_lv       = (const float*)d_in[16];
    const float* b_lv       = (const float*)d_in[17];
    const float* w_dec      = (const float*)d_in[18];
    const float* b_dec      = (const float*)d_in[19];
    const float* veps       = (const float*)d_in[20];
    const float* w1         = (const float*)d_in[21];
    const float* a_src1     = (const float*)d_in[22];
    const float* a_dst1     = (const float*)d_in[23];
    const float* b1         = (const float*)d_in[24];
    const float* w2         = (const float*)d_in[25];
    const float* a_src2     = (const float*)d_in[26];
    const float* a_dst2     = (const float*)d_in[27];
    const float* b2         = (const float*)d_in[28];
    float* out = (float*)d_out;

    // ---- workspace (byte offsets) ----
    char* wsb = (char*)d_ws;
    bf16_t* temb_bf = (bf16_t*)(wsb + 0);                 // 19.2 MB
    float*  mlbuf   = (float*)(wsb + 56064000);
    float*  recb    = (float*)(wsb + 64256000);
    bf16_t* xp1b    = (bf16_t*)(wsb + 0);                 // GAT alias in temb
    bf16_t* x1b     = (bf16_t*)(wsb + 20480000);
    float*  xp2     = (float*)(wsb + 30720000);
    bf16_t* wih0_bf = (bf16_t*)(wsb + 92928000);
    bf16_t* whh0_bf = (bf16_t*)(wsb + 93419520);
    bf16_t* wih1_bf = (bf16_t*)(wsb + 93812736);
    bf16_t* whh1_bf = (bf16_t*)(wsb + 94205952);
    bf16_t* wml_bf  = (bf16_t*)(wsb + 94599168);
    bf16_t* wdec_bf = (bf16_t*)(wsb + 95123456);
    bf16_t* w1t_bf  = (bf16_t*)(wsb + 95385600);
    bf16_t* w2t_bf  = (bf16_t*)(wsb + 95648000);
    float*  b_ml    = (float*)(wsb + 95750400);
    bf16_t* ufeats_bf = (bf16_t*)(wsb + 95752448);
    bf16_t* h0b_init = (bf16_t*)(wsb + 124424448);
    bf16_t* h1init  = (bf16_t*)(wsb + 127496448);
    bf16_t* h1sA    = (bf16_t*)(wsb + 130568448);
    bf16_t* xin_bf  = (bf16_t*)(wsb + 136712448);
    int*    deg     = (int*)(wsb + 141832448);
    int*    dcnt    = (int*)(wsb + 141872448);
    int*    rowptr  = (int*)(wsb + 141912448);
    int*    csrc    = (int*)(wsb + 141952512);
    float*  asn1    = (float*)(wsb + 142312512);
    float*  adn1    = (float*)(wsb + 142632512);
    float*  asn2    = (float*)(wsb + 142952512);
    float*  adn2    = (float*)(wsb + 142992512);

    const int TB = 256;
    auto blocks = [](int n) { return (n + 255) / 256; };

    auto mkcfg = [](const bf16_t* A, const bf16_t* B, const float* bias,
                    float* Cf, bf16_t* Cb, int M, int N, int K, int ldc,
                    const int* gtok, int t0) {
        GCfg g; g.A = A; g.B = B; g.bias = bias; g.Cf = Cf; g.Cb = Cb;
        g.M = M; g.N = N; g.K = K; g.ldc = ldc; g.gtok = gtok; g.t0 = t0;
        return g;
    };
    auto launch_bf = [&](GCfg g0) {
        dim3 grid((g0.N + 127) / 128, (g0.M + 127) / 128, 1);
        hipLaunchKernelGGL((mfma_gemm<true>), grid, dim3(TB), 0, stream, g0, g0);
    };
    auto launch_f32 = [&](GCfg g0) {
        dim3 grid((g0.N + 127) / 128, (g0.M + 127) / 128, 1);
        hipLaunchKernelGGL((mfma_gemm<false>), grid, dim3(TB), 0, stream, g0, g0);
    };

    // ---- prep ----
    PrepArgs pa;
    auto seg = [&](int k, const float* s, bf16_t* dst, int rows, int cin, int cout, int tr) {
        pa.seg[k] = SegD{s, dst, rows, cin, cout, tr};
    };
    seg(0, temb, temb_bf, V_, D_, DP_, 0);
    seg(1, w_ih0, wih0_bf, 3 * H_, D_, DP_, 2);   // frag-major nks=10, pad k>=300
    seg(2, w_hh0, whh0_bf, 3 * H_, H_, H_, 2);    // frag-major nks=8
    seg(3, w_ih1, wih1_bf, 3 * H_, H_, H_, 2);    // frag-major nks=8
    seg(4, w_hh1, whh1_bf, 3 * H_, H_, H_, 2);    // frag-major nks=8
    seg(5, w_mu, wml_bf, Z_, F_, F_, 0);
    seg(6, w_lv, wml_bf + (size_t)Z_ * F_, Z_, F_, F_, 0);
    seg(7, w_dec, wdec_bf, F_, Z_, Z_, 0);
    seg(8, user_feats, ufeats_bf, NU_, F_, F_, 0);
    seg(9, w1, w1t_bf, HEADS_ * H1_, 0, H_, 1);
    seg(10, w2, w2t_bf, H2_, 0, HEADS_ * H1_, 1);
    pa.nseg = 11;
    long long acc = 0;
    for (int k = 0; k < 11; k++) {
        pa.base[k] = acc;
        acc += (long long)pa.seg[k].rows * pa.seg[k].cout;
    }
    pa.base[11] = acc;
    pa.total = acc;
    hipLaunchKernelGGL(prep_kern, dim3(6144), dim3(TB), 0, stream, pa);

    hipLaunchKernelGGL(init_all, dim3(blocks(NT_ * H_)), dim3(TB), 0, stream,
                       h0in, h0b_init, h1init,
                       deg, dcnt, out + N_ * H2_, b_ml, b_mu, b_lv);

    // ---- CSR build ----
    hipLaunchKernelGGL(csr_hist, dim3(blocks(E2_)), dim3(TB), 0, stream, ei, deg);
    hipLaunchKernelGGL(csr_scan, dim3(1), dim3(TB), 0, stream, deg, rowptr);
    hipLaunchKernelGGL(csr_scatter, dim3(blocks(E2_)), dim3(TB), 0, stream,
                       ei, rowptr, dcnt, csrc);

    // ---- VAE ----
    launch_f32(mkcfg(ufeats_bf, wml_bf, b_ml, mlbuf, nullptr,
                     NU_, 2 * Z_, F_, 2 * Z_, nullptr, 0));
    bf16_t* z_bf = xin_bf + (size_t)B_ * H_;
    hipLaunchKernelGGL(vae_z_kl, dim3(256), dim3(TB), 0, stream,
                       mlbuf, veps, z_bf, out + N_ * H2_);
    launch_f32(mkcfg(z_bf, wdec_bf, b_dec, recb, nullptr,
                     NU_, F_, Z_, F_, nullptr, 0));
    hipLaunchKernelGGL(rec_loss_kern, dim3(256), dim3(TB), 0, stream,
                       recb, user_feats, out + N_ * H2_ + 1);

    // ---- 2-layer GRU: ONE fused kernel over all 24 steps, both layers ----
    {
        MegaLay ML;
        ML.temb = temb_bf; ML.gnf = gnf;
        ML.wih0 = wih0_bf; ML.whh0 = whh0_bf;
        ML.wih1 = wih1_bf; ML.whh1 = whh1_bf;
        ML.bih0 = b_ih0; ML.bhh0 = b_hh0; ML.bih1 = b_ih1; ML.bhh1 = b_hh1;
        ML.h0in = h0b_init; ML.h1in = h1init; ML.h1out = h1sA;
        hipLaunchKernelGGL(gru_mega, dim3((NT_ + 31) / 32), dim3(1024), 0, stream, ML);
    }

    // ---- assemble x_in ----
    hipLaunchKernelGGL(assemble_xin, dim3(blocks(NT_ * H_)), dim3(TB), 0, stream,
                       h1sA, xin_bf);

    // ---- GAT layer 1 (xp1 in bf16) ----
    launch_bf(mkcfg(xin_bf, w1t_bf, nullptr, nullptr, xp1b,
                    N_, HEADS_ * H1_, H_, HEADS_ * H1_, nullptr, 0));
    hipLaunchKernelGGL(gat_attn_coef_bf, dim3(blocks(N_ * HEADS_)), dim3(TB), 0, stream,
                       xp1b, a_src1, a_dst1, asn1, adn1, HEADS_, H1_);
    hipLaunchKernelGGL(gat_agg1, dim3(N_), dim3(TB), 0, stream,
                       rowptr, csrc, asn1, adn1, xp1b, b1, x1b);

    // ---- GAT layer 2 ----
    launch_f32(mkcfg(x1b, w2t_bf, nullptr, xp2, nullptr,
                     N_, H2_, HEADS_ * H1_, H2_, nullptr, 0));
    hipLaunchKernelGGL(gat_attn_coef, dim3(blocks(N_)), dim3(TB), 0, stream,
                       xp2, a_src2, a_dst2, asn2, adn2, 1, H2_);
    hipLaunchKernelGGL(gat_agg2, dim3((N_ + 3) / 4), dim3(TB), 0, stream,
                       rowptr, csrc, asn2, adn2, xp2, b2, out);

    (void)in_sizes; (void)n_in; (void)out_size; (void)ws_size;
}

// Round 12
// 835.777 us; speedup vs baseline: 1.0281x; 1.0281x over previous
//
#include <hip/hip_runtime.h>

// ---- problem dims (fixed by reference) ----
#define V_ 30000
#define D_ 300
#define DP_ 320
#define T_ 24
#define H_ 256
#define NT_ 6000
#define NU_ 4000
#define N_ 10000
#define F_ 512
#define Z_ 256
#define E_ 80000
#define B_ 2000
#define H1_ 64
#define H2_ 100
#define HEADS_ 8
#define E2_ (E_ + N_)

typedef __bf16 bf16_t;
typedef bf16_t bf16x8 __attribute__((ext_vector_type(8)));
typedef float  f32x4  __attribute__((ext_vector_type(4)));

// async global->LDS, 16B per lane; lds dest = base + lane*16 (wave-uniform base)
__device__ __forceinline__ void gll16(const bf16_t* g, bf16_t* l)
{
    __builtin_amdgcn_global_load_lds(
        (const __attribute__((address_space(1))) void*)g,
        (__attribute__((address_space(3))) void*)l, 16, 0, 0);
}

// =======================================================================
// 128x128 MFMA GEMM: C = A[M,K] @ B[N,K]^T (+bias).  (R14 2-buffer loop)
// =======================================================================
struct GCfg {
    const bf16_t* A; const bf16_t* B; const float* bias;
    float* Cf; bf16_t* Cb; int M, N, K, ldc;
    const int* gtok; int t0;
};

template<bool OUTBF>
__global__ __launch_bounds__(256) void mfma_gemm(GCfg g0, GCfg g1)
{
    const GCfg g = blockIdx.z ? g1 : g0;
    __shared__ __align__(16) bf16_t SMEM[16384];   // 32 KB
    const int tid  = (int)threadIdx.x;
    const int wave = tid >> 6, lane = tid & 63;
    const int quad = lane >> 4, l16 = lane & 15;
    const int mq = (wave & 1) * 64, nq = (wave >> 1) * 64;

    int bx = (int)blockIdx.x, by = (int)blockIdx.y;
    {
        int gx = (int)gridDim.x, total = gx * (int)gridDim.y;
        if ((total & 7) == 0) {
            int L = by * gx + bx;
            int F = (L & 7) * (total >> 3) + (L >> 3);
            bx = F % gx;
            by = F / gx;
        }
    }
    const int mbase = by * 128, nbase = bx * 128;
    const int M = g.M, N = g.N, K = g.K, ldc = g.ldc;

    const bf16_t* agp[2];
    const bf16_t* bgp[2];
#pragma unroll
    for (int j = 0; j < 2; j++) {
        int i = wave * 128 + j * 64 + lane;
        int c = i >> 7, row = i & 127;
        int r = mbase + row; if (r >= M) r = M - 1;
        int src = g.gtok ? g.gtok[(r % NT_) * T_ + g.t0 + (r / NT_)] : r;
        agp[j] = g.A + (size_t)src * K + c * 8;
        int rb = nbase + row; if (rb >= N) rb = N - 1;
        bgp[j] = g.B + (size_t)rb * K + c * 8;
    }

    f32x4 acc[4][4];
#pragma unroll
    for (int mi = 0; mi < 4; mi++)
#pragma unroll
        for (int ni = 0; ni < 4; ni++) acc[mi][ni] = (f32x4){0.f, 0.f, 0.f, 0.f};

    auto stage = [&](int b, int k0) {
        bf16_t* ab = SMEM + b * 4096 + wave * 1024;
        bf16_t* bb = SMEM + 8192 + b * 4096 + wave * 1024;
        gll16(agp[0] + k0, ab);
        gll16(agp[1] + k0, ab + 512);
        gll16(bgp[0] + k0, bb);
        gll16(bgp[1] + k0, bb + 512);
    };

    const int niter = K >> 5;
    stage(0, 0);
    for (int ks = 0; ks < niter; ks++) {
        __syncthreads();
        if (ks + 1 < niter) stage((ks + 1) & 1, (ks + 1) * 32);
        const bf16_t* Ab = SMEM + (ks & 1) * 4096;
        const bf16_t* Bb = SMEM + 8192 + (ks & 1) * 4096;
        bf16x8 afr[4], bfr[4];
#pragma unroll
        for (int mi = 0; mi < 4; mi++)
            afr[mi] = *(const bf16x8*)(Ab + (size_t)(quad * 128 + mq + mi * 16 + l16) * 8);
#pragma unroll
        for (int ni = 0; ni < 4; ni++)
            bfr[ni] = *(const bf16x8*)(Bb + (size_t)(quad * 128 + nq + ni * 16 + l16) * 8);
#pragma unroll
        for (int mi = 0; mi < 4; mi++)
#pragma unroll
            for (int ni = 0; ni < 4; ni++)
                acc[mi][ni] = __builtin_amdgcn_mfma_f32_16x16x32_bf16(
                    afr[mi], bfr[ni], acc[mi][ni], 0, 0, 0);
    }

    if (OUTBF) {
        __syncthreads();
#pragma unroll
        for (int ni = 0; ni < 4; ni++) {
            int colc = nq + ni * 16 + l16;
            float bv = g.bias ? g.bias[nbase + colc] : 0.f;
            int cc = colc >> 3, off = colc & 7;
#pragma unroll
            for (int mi = 0; mi < 4; mi++)
#pragma unroll
                for (int r = 0; r < 4; r++) {
                    int row = mq + mi * 16 + quad * 4 + r;
                    int sw = (row ^ (row >> 3)) & 7;
                    SMEM[row * 128 + ((cc ^ sw) << 3) + off] =
                        (bf16_t)(acc[mi][ni][r] + bv);
                }
        }
        __syncthreads();
        {
            int row = tid >> 1, seg = tid & 1;
            int sw = (row ^ (row >> 3)) & 7;
            int growr = mbase + row;
            if (growr < M) {
#pragma unroll
                for (int q = 0; q < 8; q++) {
                    int cc = seg * 8 + q;
                    bf16x8 v = *(const bf16x8*)(SMEM + row * 128 + ((cc ^ sw) << 3));
                    *(bf16x8*)(g.Cb + (size_t)growr * ldc + nbase + cc * 8) = v;
                }
            }
        }
    } else {
#pragma unroll
        for (int ni = 0; ni < 4; ni++) {
            int col = nbase + nq + ni * 16 + l16;
            if (col >= N) continue;
            float bv = g.bias ? g.bias[col] : 0.f;
#pragma unroll
            for (int mi = 0; mi < 4; mi++)
#pragma unroll
                for (int r = 0; r < 4; r++) {
                    int row = mbase + mq + mi * 16 + quad * 4 + r;
                    if (row >= M) continue;
                    g.Cf[(size_t)row * ldc + col] = acc[mi][ni][r] + bv;
                }
        }
    }
}

// =======================================================================
// R21: gru_mega back on the BENCHED R17 geometry (512 thr, 32 rows,
// 8 waves x 32 cols) + vocabulary-Gi precompute.
// R19/R20 (64-row, 110-150KB LDS) failed to launch twice, cause unknown
// -> revert to the proven structure. New lever: xe@Wih0^T depends only
// on the TOKEN, so vocGi[30000][768] = temb@Wih0^T + b_ih0 is computed
// ONCE by the proven mfma_gemm (sequential rows, ~45us). gru_mega then
// drops the wih0 GEMM (10 of 34 ks iters, 480KB/step weight stream) and
// the whole xe gather/XE buffer; the Gi0 term becomes 48 prefetched
// scalar reads per thread (issued at step top, consumed post-GEMM ->
// latency hidden). LDS 75KB -> 35KB; 3 barriers/step instead of 4.
// Per-block/step traffic 1.71MB -> ~1.28MB (-25%).
// =======================================================================
struct MegaLay {
    const bf16_t* vocGi;   // [V][768] = temb@Wih0^T + b_ih0
    const int*    gnf;     // [NT][24]
    const bf16_t* whh0;    // frag-major, nks=8
    const bf16_t* wih1;    // frag-major, nks=8
    const bf16_t* whh1;    // frag-major, nks=8
    const float *bhh0, *bih1, *bhh1;
    const bf16_t* h0in;    // [NT][256]
    const bf16_t* h1in;
    bf16_t*       h1out;   // final h1
};

__device__ __forceinline__ float rcp_(float x)
{
    float r;
    asm("v_rcp_f32 %0, %1" : "=v"(r) : "v"(x));
    return r;
}
__device__ __forceinline__ float sigm_(float x)
{
    return rcp_(1.f + __expf(-x));
}
__device__ __forceinline__ float tanh_(float x)
{
    x = fminf(fmaxf(x, -15.f), 15.f);
    float t = __expf(2.f * x);
    return 1.f - 2.f * rcp_(t + 1.f);
}

// swizzled LDS addr for h tile [32 rows][512B]: XOR row into byte bits 4-6
#define HSW(Hb, row, byte) ((char*)(Hb) + ((((row) * 512) + (byte)) ^ (((row) & 7) << 4)))

__global__ __launch_bounds__(512, 1) void gru_mega(MegaLay L)
{
    __shared__ __align__(16) bf16_t H0L[8192];    // 16 KB h0[32][256] swizzled
    __shared__ __align__(16) bf16_t H1L[8192];    // 16 KB h1[32][256] swizzled
    __shared__ int TOK[768];                      // 3 KB  tokens [32][24]
    const int tid  = (int)threadIdx.x;
    const int wv   = tid >> 6, lane = tid & 63;   // wv 0..7
    const int quad = lane >> 4, l16 = lane & 15;
    const int row0 = (int)blockIdx.x * 32;

    // ---- tokens + initial h into swizzled LDS ----
    for (int i = tid; i < 768; i += 512) {
        int gi = row0 * T_ + i; if (gi >= NT_ * T_) gi = NT_ * T_ - 1;
        TOK[i] = L.gnf[gi];
    }
#pragma unroll
    for (int i = 0; i < 2; i++) {
        int idx  = i * 512 + tid;
        int rowl = idx >> 5, seg = idx & 31;
        int grow = row0 + rowl; if (grow >= NT_) grow = NT_ - 1;
        *(bf16x8*)HSW(H0L, rowl, seg * 16) =
            *(const bf16x8*)(L.h0in + (size_t)grow * H_ + seg * 8);
        *(bf16x8*)HSW(H1L, rowl, seg * 16) =
            *(const bf16x8*)(L.h1in + (size_t)grow * H_ + seg * 8);
    }

    // per-lane biases for this wave's 32-col slice.
    // L0: Gi carries b_ih0 already -> only bhh0 here. L1: r,z combined.
    float bh0[3][2], brz1[2][2], bni1[2], bnh1[2];
#pragma unroll
    for (int jj = 0; jj < 2; jj++) {
        int col = wv * 32 + jj * 16 + l16;
        bh0[0][jj] = L.bhh0[col];
        bh0[1][jj] = L.bhh0[256 + col];
        bh0[2][jj] = L.bhh0[512 + col];
        brz1[0][jj] = L.bih1[col] + L.bhh1[col];
        brz1[1][jj] = L.bih1[256 + col] + L.bhh1[256 + col];
        bni1[jj]    = L.bih1[512 + col];
        bnh1[jj]    = L.bhh1[512 + col];
    }

    // generic K-loop: A-frags via loader, B-frags frag-major from L2.
    auto run_gemm = [&](auto&& loadA, const bf16_t* W,
                        f32x4 (&arz)[2][2][2], f32x4 (&an)[2][2]) {
#pragma unroll 2
        for (int ks = 0; ks < 8; ks++) {
            bf16x8 bfr[3][2];
#pragma unroll
            for (int g = 0; g < 3; g++)
#pragma unroll
                for (int jj = 0; jj < 2; jj++)
                    bfr[g][jj] = *(const bf16x8*)(W +
                        (((size_t)(g * 16 + wv * 2 + jj) * 8 + ks) << 9) + lane * 8);
            bf16x8 afr[2];
            loadA(afr, ks);
#pragma unroll
            for (int m = 0; m < 2; m++)
#pragma unroll
                for (int jj = 0; jj < 2; jj++) {
                    arz[m][0][jj] = __builtin_amdgcn_mfma_f32_16x16x32_bf16(
                        afr[m], bfr[0][jj], arz[m][0][jj], 0, 0, 0);
                    arz[m][1][jj] = __builtin_amdgcn_mfma_f32_16x16x32_bf16(
                        afr[m], bfr[1][jj], arz[m][1][jj], 0, 0, 0);
                    an[m][jj] = __builtin_amdgcn_mfma_f32_16x16x32_bf16(
                        afr[m], bfr[2][jj], an[m][jj], 0, 0, 0);
                }
        }
    };

    __syncthreads();          // TOK + h visible

    for (int t = 0; t < T_; t++) {
        // ---- prefetch this step's Gi0 scalars (vocGi rows by token).
        // Addresses depend only on TOK; loads land during the whh0 GEMM.
        float gi[2][2][4][3];
#pragma unroll
        for (int m = 0; m < 2; m++)
#pragma unroll
            for (int r2 = 0; r2 < 4; r2++) {
                int rowl = m * 16 + quad * 4 + r2;
                const bf16_t* gp = L.vocGi +
                    (size_t)TOK[rowl * T_ + t] * (3 * H_);
#pragma unroll
                for (int jj = 0; jj < 2; jj++) {
                    int col = wv * 32 + jj * 16 + l16;
#pragma unroll
                    for (int g = 0; g < 3; g++)
                        gi[m][jj][r2][g] = (float)gp[g * 256 + col];
                }
            }

        f32x4 arz[2][2][2], an_i[2][2], an_h[2][2];
#pragma unroll
        for (int m = 0; m < 2; m++)
#pragma unroll
            for (int jj = 0; jj < 2; jj++) {
                arz[m][0][jj] = (f32x4){0.f, 0.f, 0.f, 0.f};
                arz[m][1][jj] = (f32x4){0.f, 0.f, 0.f, 0.f};
                an_h[m][jj]   = (f32x4){0.f, 0.f, 0.f, 0.f};
            }

        // ---- layer 0: only Gh0 = h0 @ Whh0^T (Gi0 is prefetched) ----
        run_gemm([&](bf16x8* afr, int ks) {
#pragma unroll
            for (int m = 0; m < 2; m++)
                afr[m] = *(const bf16x8*)HSW(H0L, m * 16 + l16,
                                             ks * 64 + quad * 16);
        }, L.whh0, arz, an_h);
        __syncthreads();      // all h0 reads done

        // ---- gates L0 -> h0 in place ----
#pragma unroll
        for (int m = 0; m < 2; m++)
#pragma unroll
            for (int jj = 0; jj < 2; jj++) {
                int col = wv * 32 + jj * 16 + l16;
#pragma unroll
                for (int r = 0; r < 4; r++) {
                    int rowl = m * 16 + quad * 4 + r;
                    float hold = (float)*(const bf16_t*)HSW(H0L, rowl, col * 2);
                    float rg = sigm_(gi[m][jj][r][0] + arz[m][0][jj][r] + bh0[0][jj]);
                    float zg = sigm_(gi[m][jj][r][1] + arz[m][1][jj][r] + bh0[1][jj]);
                    float ng = tanh_(gi[m][jj][r][2] +
                                     rg * (an_h[m][jj][r] + bh0[2][jj]));
                    *(bf16_t*)HSW(H0L, rowl, col * 2) =
                        (bf16_t)((1.f - zg) * ng + zg * hold);
                }
            }
        __syncthreads();      // new h0 visible

        // ---- layer 1: Gi1 (h0 new) + Gh1 (h1) ----
#pragma unroll
        for (int m = 0; m < 2; m++)
#pragma unroll
            for (int jj = 0; jj < 2; jj++) {
                arz[m][0][jj] = (f32x4){0.f, 0.f, 0.f, 0.f};
                arz[m][1][jj] = (f32x4){0.f, 0.f, 0.f, 0.f};
                an_i[m][jj]   = (f32x4){0.f, 0.f, 0.f, 0.f};
                an_h[m][jj]   = (f32x4){0.f, 0.f, 0.f, 0.f};
            }
        run_gemm([&](bf16x8* afr, int ks) {
#pragma unroll
            for (int m = 0; m < 2; m++)
                afr[m] = *(const bf16x8*)HSW(H0L, m * 16 + l16,
                                             ks * 64 + quad * 16);
        }, L.wih1, arz, an_i);
        run_gemm([&](bf16x8* afr, int ks) {
#pragma unroll
            for (int m = 0; m < 2; m++)
                afr[m] = *(const bf16x8*)HSW(H1L, m * 16 + l16,
                                             ks * 64 + quad * 16);
        }, L.whh1, arz, an_h);
        __syncthreads();      // all h0/h1 reads done

        // ---- gates L1 -> h1 in place ----
#pragma unroll
        for (int m = 0; m < 2; m++)
#pragma unroll
            for (int jj = 0; jj < 2; jj++) {
                int col = wv * 32 + jj * 16 + l16;
#pragma unroll
                for (int r = 0; r < 4; r++) {
                    int rowl = m * 16 + quad * 4 + r;
                    float hold = (float)*(const bf16_t*)HSW(H1L, rowl, col * 2);
                    float rg = sigm_(arz[m][0][jj][r] + brz1[0][jj]);
                    float zg = sigm_(arz[m][1][jj][r] + brz1[1][jj]);
                    float ng = tanh_(an_i[m][jj][r] + bni1[jj] +
                                     rg * (an_h[m][jj][r] + bnh1[jj]));
                    *(bf16_t*)HSW(H1L, rowl, col * 2) =
                        (bf16_t)((1.f - zg) * ng + zg * hold);
                }
            }
        // next iteration's first barrier separates these writes from the
        // next step's H1L reads (which occur after two more barriers).
    }

    __syncthreads();
#pragma unroll
    for (int i = 0; i < 2; i++) {
        int idx  = i * 512 + tid;
        int rowl = idx >> 5, seg = idx & 31;
        int grow = row0 + rowl;
        if (grow < NT_) {
            bf16x8 v = *(const bf16x8*)HSW(H1L, rowl, seg * 16);
            *(bf16x8*)(L.h1out + (size_t)grow * H_ + seg * 8) = v;
        }
    }
}

// ---------------- prep: all f32->bf16 conversions in one launch ----------------
// transp: 0 = row-major (pad cols), 1 = transpose, 2 = fragment-major
//         (nks = cout/32; cin = src inner dim, zero-pad kk >= cin)
struct SegD { const float* src; bf16_t* dst; int rows, cin, cout, transp; };
struct PrepArgs { SegD seg[11]; long long base[12]; int nseg; long long total; };

__global__ void prep_kern(PrepArgs pa)
{
    long long stride = (long long)gridDim.x * blockDim.x;
    for (long long i = (long long)blockIdx.x * blockDim.x + threadIdx.x;
         i < pa.total; i += stride) {
        int k = 0;
        while (k + 1 < pa.nseg && i >= pa.base[k + 1]) k++;
        long long local = i - pa.base[k];
        SegD sg = pa.seg[k];
        float v;
        if (sg.transp == 2) {
            int nks  = sg.cout >> 5;
            int o    = (int)local;
            int e    = o & 7;
            int lane = (o >> 3) & 63;
            int rest = o >> 9;
            int ks   = rest % nks;
            int gcb  = rest / nks;
            int r    = (gcb >> 4) * 256 + (gcb & 15) * 16 + (lane & 15);
            int kk   = ks * 32 + (lane >> 4) * 8 + e;
            v = (kk < sg.cin) ? sg.src[(size_t)r * sg.cin + kk] : 0.f;
        } else {
            int r = (int)(local / sg.cout);
            int c = (int)(local - (long long)r * sg.cout);
            if (sg.transp) v = sg.src[(size_t)c * sg.rows + r];
            else           v = (c < sg.cin) ? sg.src[(size_t)r * sg.cin + c] : 0.f;
        }
        sg.dst[local] = (bf16_t)v;
    }
}

// ---------------- fused init ----------------
__global__ void init_all(const float* __restrict__ h0in, bf16_t* __restrict__ h0b,
                         bf16_t* __restrict__ h1b,
                         int* __restrict__ deg, int* __restrict__ dcnt,
                         float* __restrict__ loss2, float* __restrict__ b_ml,
                         const float* __restrict__ b_mu, const float* __restrict__ b_lv)
{
    int i = blockIdx.x * blockDim.x + threadIdx.x;
    if (i < NT_ * H_) {
        h0b[i] = (bf16_t)h0in[i];
        h1b[i] = (bf16_t)h0in[NT_ * H_ + i];
    }
    if (i < N_) { deg[i] = 0; dcnt[i] = 0; }
    if (i < 2 * Z_) b_ml[i] = (i < Z_) ? b_mu[i] : b_lv[i - Z_];
    if (i < 2) loss2[i] = 0.f;
}

// ---------------- CSR build (by dst, self-loops appended) ----------------
__device__ __forceinline__ void edge_sd(const int* __restrict__ ei, int e, int& s, int& d)
{
    if (e < E_) { s = ei[e]; d = ei[E_ + e]; }
    else        { s = d = e - E_; }
}

__global__ void csr_hist(const int* __restrict__ ei, int* __restrict__ deg)
{
    int e = blockIdx.x * blockDim.x + threadIdx.x;
    if (e >= E2_) return;
    int s, d; edge_sd(ei, e, s, d);
    atomicAdd(deg + d, 1);
}

__global__ void csr_scan(const int* __restrict__ deg, int* __restrict__ rowptr)
{
    __shared__ int buf[256];
    __shared__ int carry;
    int tid = (int)threadIdx.x;
    if (tid == 0) { carry = 0; rowptr[0] = 0; }
    __syncthreads();
    for (int c0 = 0; c0 < N_; c0 += 256) {
        int i = c0 + tid;
        buf[tid] = (i < N_) ? deg[i] : 0;
        __syncthreads();
        for (int off = 1; off < 256; off <<= 1) {
            int t = (tid >= off) ? buf[tid - off] : 0;
            __syncthreads();
            buf[tid] += t;
            __syncthreads();
        }
        if (i < N_) rowptr[i + 1] = carry + buf[tid];
        __syncthreads();
        if (tid == 255) carry += buf[255];
        __syncthreads();
    }
}

__global__ void csr_scatter(const int* __restrict__ ei, const int* __restrict__ rowptr,
                            int* __restrict__ dcnt, int* __restrict__ csrc)
{
    int e = blockIdx.x * blockDim.x + threadIdx.x;
    if (e >= E2_) return;
    int s, d; edge_sd(ei, e, s, d);
    int pos = rowptr[d] + atomicAdd(dcnt + d, 1);
    csrc[pos] = s;
}

// ---------------- VAE (grid-stride; 256 atomics) ----------------
__global__ __launch_bounds__(256) void vae_z_kl(
    const float* __restrict__ ml, const float* __restrict__ eps,
    bf16_t* __restrict__ z_out, float* __restrict__ kl_out)
{
    float t = 0.f;
    int stride = (int)gridDim.x * 256;
    for (int idx = blockIdx.x * 256 + threadIdx.x; idx < NU_ * Z_; idx += stride) {
        int row = idx >> 8, c = idx & 255;
        float m = ml[(size_t)row * 512 + c];
        float l = ml[(size_t)row * 512 + 256 + c];
        float el = expf(l);
        z_out[idx] = (bf16_t)(m + expf(0.5f * l) * eps[idx]);
        t += -0.5f * (1.f + l - m * m - el);
    }
    __shared__ float red[256];
    red[threadIdx.x] = t;
    __syncthreads();
    for (int s = 128; s > 0; s >>= 1) {
        if ((int)threadIdx.x < s) red[threadIdx.x] += red[threadIdx.x + s];
        __syncthreads();
    }
    if (threadIdx.x == 0) atomicAdd(kl_out, red[0] * (1.f / NU_));
}

__global__ __launch_bounds__(256) void rec_loss_kern(
    const float* __restrict__ rec, const float* __restrict__ uf,
    float* __restrict__ loss_out)
{
    float t = 0.f;
    int stride = (int)gridDim.x * 256;
    for (int idx = blockIdx.x * 256 + threadIdx.x; idx < NU_ * F_; idx += stride) {
        float d = rec[idx] - uf[idx];
        t += d * d;
    }
    __shared__ float red[256];
    red[threadIdx.x] = t;
    __syncthreads();
    for (int s = 128; s > 0; s >>= 1) {
        if ((int)threadIdx.x < s) red[threadIdx.x] += red[threadIdx.x + s];
        __syncthreads();
    }
    if (threadIdx.x == 0) atomicAdd(loss_out, red[0] * (1.f / (NU_ * F_)));
}

// ---------------- assemble x_in = [hn[:B], z, hn[B:]] (bf16 -> bf16) ----------------
__global__ void assemble_xin(const bf16_t* __restrict__ h1, bf16_t* __restrict__ x_in)
{
    int idx = blockIdx.x * blockDim.x + threadIdx.x;
    if (idx >= NT_ * H_) return;
    int row = idx >> 8, col = idx & 255;
    int dst = (row < B_) ? row : (row + NU_);
    x_in[(size_t)dst * H_ + col] = h1[idx];
}

// ---------------- GAT ----------------
__global__ void gat_attn_coef_bf(const bf16_t* __restrict__ xp,
                                 const float* __restrict__ a_src,
                                 const float* __restrict__ a_dst,
                                 float* __restrict__ asn, float* __restrict__ adn,
                                 int heads, int C)
{
    int i = blockIdx.x * blockDim.x + threadIdx.x;
    if (i >= N_ * heads) return;
    int node = i / heads, h = i - node * heads;
    const bf16_t* x = xp + (size_t)(node * heads + h) * C;
    float s = 0.f, d = 0.f;
    for (int c8 = 0; c8 < C; c8 += 8) {
        bf16x8 v = *(const bf16x8*)(x + c8);
#pragma unroll
        for (int j = 0; j < 8; j++) {
            float vv = (float)v[j];
            s += vv * a_src[h * C + c8 + j];
            d += vv * a_dst[h * C + c8 + j];
        }
    }
    asn[i] = s;
    adn[i] = d;
}

__global__ void gat_attn_coef(const float* __restrict__ xp, const float* __restrict__ a_src,
                              const float* __restrict__ a_dst, float* __restrict__ asn,
                              float* __restrict__ adn, int heads, int C)
{
    int i = blockIdx.x * blockDim.x + threadIdx.x;
    if (i >= N_ * heads) return;
    int node = i / heads, h = i - node * heads;
    const float* x = xp + (size_t)(node * heads + h) * C;
    float s = 0.f, d = 0.f;
    for (int c = 0; c < C; c++) {
        float v = x[c];
        s += v * a_src[h * C + c];
        d += v * a_dst[h * C + c];
    }
    asn[i] = s;
    adn[i] = d;
}

// fused edge-softmax + aggregate, layer 1: BLOCK per dst, all 8 heads.
__global__ __launch_bounds__(256) void gat_agg1(
    const int* __restrict__ rowptr, const int* __restrict__ csrc,
    const float* __restrict__ asn, const float* __restrict__ adn,
    const bf16_t* __restrict__ xp, const float* __restrict__ bias,
    bf16_t* __restrict__ x1out)
{
    int d = blockIdx.x;
    int tid = (int)threadIdx.x;
    int beg = rowptr[d], end = rowptr[d + 1];
    int h0 = tid >> 6, h1 = h0 + 4;
    float ad0 = adn[d * 8 + h0], ad1 = adn[d * 8 + h1];
    float mx0 = -1e30f, mx1 = -1e30f;
    for (int e = beg; e < end; e++) {
        int s = csrc[e];
        float l0 = asn[s * 8 + h0] + ad0; l0 = (l0 > 0.f) ? l0 : 0.2f * l0;
        float l1 = asn[s * 8 + h1] + ad1; l1 = (l1 > 0.f) ? l1 : 0.2f * l1;
        mx0 = fmaxf(mx0, l0); mx1 = fmaxf(mx1, l1);
    }
    float den0 = 0.f, den1 = 0.f, acc0 = 0.f, acc1 = 0.f;
    for (int e = beg; e < end; e++) {
        int s = csrc[e];
        float l0 = asn[s * 8 + h0] + ad0; l0 = (l0 > 0.f) ? l0 : 0.2f * l0;
        float l1 = asn[s * 8 + h1] + ad1; l1 = (l1 > 0.f) ? l1 : 0.2f * l1;
        float p0 = expf(l0 - mx0), p1 = expf(l1 - mx1);
        den0 += p0; den1 += p1;
        acc0 += p0 * (float)xp[(size_t)s * 512 + tid];
        acc1 += p1 * (float)xp[(size_t)s * 512 + 256 + tid];
    }
    x1out[(size_t)d * 512 + tid]       = (bf16_t)(bias[tid] + acc0 / den0);
    x1out[(size_t)d * 512 + 256 + tid] = (bf16_t)(bias[256 + tid] + acc1 / den1);
}

// fused edge-softmax + aggregate, layer 2 (1 head x 100ch): wave per dst
__global__ __launch_bounds__(256) void gat_agg2(
    const int* __restrict__ rowptr, const int* __restrict__ csrc,
    const float* __restrict__ asn, const float* __restrict__ adn,
    const float* __restrict__ xp, const float* __restrict__ bias,
    float* __restrict__ outp)
{
    int d = blockIdx.x * 4 + ((int)threadIdx.x >> 6);
    if (d >= N_) return;
    int lane = (int)threadIdx.x & 63;
    int beg = rowptr[d], end = rowptr[d + 1];
    float adnd = adn[d];
    float mx = -1e30f;
    for (int e = beg; e < end; e++) {
        float l = asn[csrc[e]] + adnd;
        l = (l > 0.f) ? l : 0.2f * l;
        mx = fmaxf(mx, l);
    }
    float den = 0.f, acc0 = 0.f, acc1 = 0.f;
    for (int e = beg; e < end; e++) {
        int s = csrc[e];
        float l = asn[s] + adnd;
        l = (l > 0.f) ? l : 0.2f * l;
        float p = expf(l - mx);
        den += p;
        acc0 += p * xp[(size_t)s * H2_ + lane];
        if (lane < H2_ - 64) acc1 += p * xp[(size_t)s * H2_ + 64 + lane];
    }
    outp[(size_t)d * H2_ + lane] = bias[lane] + acc0 / den;
    if (lane < H2_ - 64)
        outp[(size_t)d * H2_ + 64 + lane] = bias[64 + lane] + acc1 / den;
}

// ---------------- launcher ----------------
extern "C" void kernel_launch(void* const* d_in, const int* in_sizes, int n_in,
                              void* d_out, int out_size, void* d_ws, size_t ws_size,
                              hipStream_t stream)
{
    const float* user_feats = (const float*)d_in[1];
    const int*   gnf        = (const int*)d_in[2];
    const int*   ei         = (const int*)d_in[3];
    const float* temb       = (const float*)d_in[4];
    const float* w_ih0      = (const float*)d_in[5];
    const float* w_hh0      = (const float*)d_in[6];
    const float* b_ih0      = (const float*)d_in[7];
    const float* b_hh0      = (const float*)d_in[8];
    const float* w_ih1      = (const float*)d_in[9];
    const float* w_hh1      = (const float*)d_in[10];
    const float* b_ih1      = (const float*)d_in[11];
    const float* b_hh1      = (const float*)d_in[12];
    const float* h0in       = (const float*)d_in[13];
    const float* w_mu       = (const float*)d_in[14];
    const float* b_mu       = (const float*)d_in[15];
    const float* w_lv       = (const float*)d_in[16];
    const float* b_lv       = (const float*)d_in[17];
    const float* w_dec      = (const float*)d_in[18];
    const float* b_dec      = (const float*)d_in[19];
    const float* veps       = (const float*)d_in[20];
    const float* w1         = (const float*)d_in[21];
    const float* a_src1     = (const float*)d_in[22];
    const float* a_dst1     = (const float*)d_in[23];
    const float* b1         = (const float*)d_in[24];
    const float* w2         = (const float*)d_in[25];
    const float* a_src2     = (const float*)d_in[26];
    const float* a_dst2     = (const float*)d_in[27];
    const float* b2         = (const float*)d_in[28];
    float* out = (float*)d_out;

    // ---- workspace (byte offsets) ----
    char* wsb = (char*)d_ws;
    bf16_t* temb_bf = (bf16_t*)(wsb + 0);                 // 19.2 MB
    bf16_t* vocGi   = (bf16_t*)(wsb + 19200000);          // 46.08 MB (ends 65,280,000)
    float*  mlbuf   = (float*)(wsb + 66000000);           // 8.19 MB
    float*  recb    = (float*)(wsb + 75000000);           // 8.19 MB (ends 83,192,000)
    bf16_t* xp1b    = (bf16_t*)(wsb + 0);                 // GAT alias in temb
    bf16_t* x1b     = (bf16_t*)(wsb + 20480000);          // GAT alias in vocGi
    float*  xp2     = (float*)(wsb + 30720000);           // GAT alias in vocGi
    bf16_t* wih0_bf = (bf16_t*)(wsb + 92928000);          // row-major padded [768][320]
    bf16_t* whh0_bf = (bf16_t*)(wsb + 93419520);
    bf16_t* wih1_bf = (bf16_t*)(wsb + 93812736);
    bf16_t* whh1_bf = (bf16_t*)(wsb + 94205952);
    bf16_t* wml_bf  = (bf16_t*)(wsb + 94599168);
    bf16_t* wdec_bf = (bf16_t*)(wsb + 95123456);
    bf16_t* w1t_bf  = (bf16_t*)(wsb + 95385600);
    bf16_t* w2t_bf  = (bf16_t*)(wsb + 95648000);
    float*  b_ml    = (float*)(wsb + 95750400);
    bf16_t* ufeats_bf = (bf16_t*)(wsb + 95752448);
    bf16_t* h0b_init = (bf16_t*)(wsb + 124424448);
    bf16_t* h1init  = (bf16_t*)(wsb + 127496448);
    bf16_t* h1sA    = (bf16_t*)(wsb + 130568448);
    bf16_t* xin_bf  = (bf16_t*)(wsb + 136712448);
    int*    deg     = (int*)(wsb + 141832448);
    int*    dcnt    = (int*)(wsb + 141872448);
    int*    rowptr  = (int*)(wsb + 141912448);
    int*    csrc    = (int*)(wsb + 141952512);
    float*  asn1    = (float*)(wsb + 142312512);
    float*  adn1    = (float*)(wsb + 142632512);
    float*  asn2    = (float*)(wsb + 142952512);
    float*  adn2    = (float*)(wsb + 142992512);

    const int TB = 256;
    auto blocks = [](int n) { return (n + 255) / 256; };

    auto mkcfg = [](const bf16_t* A, const bf16_t* B, const float* bias,
                    float* Cf, bf16_t* Cb, int M, int N, int K, int ldc,
                    const int* gtok, int t0) {
        GCfg g; g.A = A; g.B = B; g.bias = bias; g.Cf = Cf; g.Cb = Cb;
        g.M = M; g.N = N; g.K = K; g.ldc = ldc; g.gtok = gtok; g.t0 = t0;
        return g;
    };
    auto launch_bf = [&](GCfg g0) {
        dim3 grid((g0.N + 127) / 128, (g0.M + 127) / 128, 1);
        hipLaunchKernelGGL((mfma_gemm<true>), grid, dim3(TB), 0, stream, g0, g0);
    };
    auto launch_f32 = [&](GCfg g0) {
        dim3 grid((g0.N + 127) / 128, (g0.M + 127) / 128, 1);
        hipLaunchKernelGGL((mfma_gemm<false>), grid, dim3(TB), 0, stream, g0, g0);
    };

    // ---- prep ----
    PrepArgs pa;
    auto seg = [&](int k, const float* s, bf16_t* dst, int rows, int cin, int cout, int tr) {
        pa.seg[k] = SegD{s, dst, rows, cin, cout, tr};
    };
    seg(0, temb, temb_bf, V_, D_, DP_, 0);
    seg(1, w_ih0, wih0_bf, 3 * H_, D_, DP_, 0);   // row-major padded (for vocGi GEMM)
    seg(2, w_hh0, whh0_bf, 3 * H_, H_, H_, 2);    // frag-major nks=8
    seg(3, w_ih1, wih1_bf, 3 * H_, H_, H_, 2);    // frag-major nks=8
    seg(4, w_hh1, whh1_bf, 3 * H_, H_, H_, 2);    // frag-major nks=8
    seg(5, w_mu, wml_bf, Z_, F_, F_, 0);
    seg(6, w_lv, wml_bf + (size_t)Z_ * F_, Z_, F_, F_, 0);
    seg(7, w_dec, wdec_bf, F_, Z_, Z_, 0);
    seg(8, user_feats, ufeats_bf, NU_, F_, F_, 0);
    seg(9, w1, w1t_bf, HEADS_ * H1_, 0, H_, 1);
    seg(10, w2, w2t_bf, H2_, 0, HEADS_ * H1_, 1);
    pa.nseg = 11;
    long long acc = 0;
    for (int k = 0; k < 11; k++) {
        pa.base[k] = acc;
        acc += (long long)pa.seg[k].rows * pa.seg[k].cout;
    }
    pa.base[11] = acc;
    pa.total = acc;
    hipLaunchKernelGGL(prep_kern, dim3(6144), dim3(TB), 0, stream, pa);

    hipLaunchKernelGGL(init_all, dim3(blocks(NT_ * H_)), dim3(TB), 0, stream,
                       h0in, h0b_init, h1init,
                       deg, dcnt, out + N_ * H2_, b_ml, b_mu, b_lv);

    // ---- CSR build ----
    hipLaunchKernelGGL(csr_hist, dim3(blocks(E2_)), dim3(TB), 0, stream, ei, deg);
    hipLaunchKernelGGL(csr_scan, dim3(1), dim3(TB), 0, stream, deg, rowptr);
    hipLaunchKernelGGL(csr_scatter, dim3(blocks(E2_)), dim3(TB), 0, stream,
                       ei, rowptr, dcnt, csrc);

    // ---- vocabulary Gi precompute: vocGi = temb @ Wih0^T + b_ih0 ----
    launch_bf(mkcfg(temb_bf, wih0_bf, b_ih0, nullptr, vocGi,
                    V_, 3 * H_, DP_, 3 * H_, nullptr, 0));

    // ---- VAE ----
    launch_f32(mkcfg(ufeats_bf, wml_bf, b_ml, mlbuf, nullptr,
                     NU_, 2 * Z_, F_, 2 * Z_, nullptr, 0));
    bf16_t* z_bf = xin_bf + (size_t)B_ * H_;
    hipLaunchKernelGGL(vae_z_kl, dim3(256), dim3(TB), 0, stream,
                       mlbuf, veps, z_bf, out + N_ * H2_);
    launch_f32(mkcfg(z_bf, wdec_bf, b_dec, recb, nullptr,
                     NU_, F_, Z_, F_, nullptr, 0));
    hipLaunchKernelGGL(rec_loss_kern, dim3(256), dim3(TB), 0, stream,
                       recb, user_feats, out + N_ * H2_ + 1);

    // ---- 2-layer GRU: ONE fused kernel over all 24 steps, both layers ----
    {
        MegaLay ML;
        ML.vocGi = vocGi; ML.gnf = gnf;
        ML.whh0 = whh0_bf; ML.wih1 = wih1_bf; ML.whh1 = whh1_bf;
        ML.bhh0 = b_hh0; ML.bih1 = b_ih1; ML.bhh1 = b_hh1;
        ML.h0in = h0b_init; ML.h1in = h1init; ML.h1out = h1sA;
        hipLaunchKernelGGL(gru_mega, dim3((NT_ + 31) / 32), dim3(512), 0, stream, ML);
    }

    // ---- assemble x_in ----
    hipLaunchKernelGGL(assemble_xin, dim3(blocks(NT_ * H_)), dim3(TB), 0, stream,
                       h1sA, xin_bf);

    // ---- GAT layer 1 (xp1 in bf16) ----
    launch_bf(mkcfg(xin_bf, w1t_bf, nullptr, nullptr, xp1b,
                    N_, HEADS_ * H1_, H_, HEADS_ * H1_, nullptr, 0));
    hipLaunchKernelGGL(gat_attn_coef_bf, dim3(blocks(N_ * HEADS_)), dim3(TB), 0, stream,
                       xp1b, a_src1, a_dst1, asn1, adn1, HEADS_, H1_);
    hipLaunchKernelGGL(gat_agg1, dim3(N_), dim3(TB), 0, stream,
                       rowptr, csrc, asn1, adn1, xp1b, b1, x1b);

    // ---- GAT layer 2 ----
    launch_f32(mkcfg(x1b, w2t_bf, nullptr, xp2, nullptr,
                     N_, H2_, HEADS_ * H1_, H2_, nullptr, 0));
    hipLaunchKernelGGL(gat_attn_coef, dim3(blocks(N_)), dim3(TB), 0, stream,
                       xp2, a_src2, a_dst2, asn2, adn2, 1, H2_);
    hipLaunchKernelGGL(gat_agg2, dim3((N_ + 3) / 4), dim3(TB), 0, stream,
                       rowptr, csrc, asn2, adn2, xp2, b2, out);

    (void)in_sizes; (void)n_in; (void)out_size; (void)ws_size;
}

// Round 13
// 794.194 us; speedup vs baseline: 1.0819x; 1.0524x over previous
//
#include <hip/hip_runtime.h>

// ---- problem dims (fixed by reference) ----
#define V_ 30000
#define D_ 300
#define DP_ 320
#define T_ 24
#define H_ 256
#define NT_ 6000
#define NU_ 4000
#define N_ 10000
#define F_ 512
#define Z_ 256
#define E_ 80000
#define B_ 2000
#define H1_ 64
#define H2_ 100
#define HEADS_ 8
#define E2_ (E_ + N_)

typedef __bf16 bf16_t;
typedef bf16_t bf16x8 __attribute__((ext_vector_type(8)));
typedef float  f32x4  __attribute__((ext_vector_type(4)));

// async global->LDS, 16B per lane; lds dest = base + lane*16 (wave-uniform base)
__device__ __forceinline__ void gll16(const bf16_t* g, bf16_t* l)
{
    __builtin_amdgcn_global_load_lds(
        (const __attribute__((address_space(1))) void*)g,
        (__attribute__((address_space(3))) void*)l, 16, 0, 0);
}

// =======================================================================
// 128x128 MFMA GEMM: C = A[M,K] @ B[N,K]^T (+bias).  (R14 2-buffer loop)
// =======================================================================
struct GCfg {
    const bf16_t* A; const bf16_t* B; const float* bias;
    float* Cf; bf16_t* Cb; int M, N, K, ldc;
    const int* gtok; int t0;
};

template<bool OUTBF>
__global__ __launch_bounds__(256) void mfma_gemm(GCfg g0, GCfg g1)
{
    const GCfg g = blockIdx.z ? g1 : g0;
    __shared__ __align__(16) bf16_t SMEM[16384];   // 32 KB
    const int tid  = (int)threadIdx.x;
    const int wave = tid >> 6, lane = tid & 63;
    const int quad = lane >> 4, l16 = lane & 15;
    const int mq = (wave & 1) * 64, nq = (wave >> 1) * 64;

    int bx = (int)blockIdx.x, by = (int)blockIdx.y;
    {
        int gx = (int)gridDim.x, total = gx * (int)gridDim.y;
        if ((total & 7) == 0) {
            int L = by * gx + bx;
            int F = (L & 7) * (total >> 3) + (L >> 3);
            bx = F % gx;
            by = F / gx;
        }
    }
    const int mbase = by * 128, nbase = bx * 128;
    const int M = g.M, N = g.N, K = g.K, ldc = g.ldc;

    const bf16_t* agp[2];
    const bf16_t* bgp[2];
#pragma unroll
    for (int j = 0; j < 2; j++) {
        int i = wave * 128 + j * 64 + lane;
        int c = i >> 7, row = i & 127;
        int r = mbase + row; if (r >= M) r = M - 1;
        int src = g.gtok ? g.gtok[(r % NT_) * T_ + g.t0 + (r / NT_)] : r;
        agp[j] = g.A + (size_t)src * K + c * 8;
        int rb = nbase + row; if (rb >= N) rb = N - 1;
        bgp[j] = g.B + (size_t)rb * K + c * 8;
    }

    f32x4 acc[4][4];
#pragma unroll
    for (int mi = 0; mi < 4; mi++)
#pragma unroll
        for (int ni = 0; ni < 4; ni++) acc[mi][ni] = (f32x4){0.f, 0.f, 0.f, 0.f};

    auto stage = [&](int b, int k0) {
        bf16_t* ab = SMEM + b * 4096 + wave * 1024;
        bf16_t* bb = SMEM + 8192 + b * 4096 + wave * 1024;
        gll16(agp[0] + k0, ab);
        gll16(agp[1] + k0, ab + 512);
        gll16(bgp[0] + k0, bb);
        gll16(bgp[1] + k0, bb + 512);
    };

    const int niter = K >> 5;
    stage(0, 0);
    for (int ks = 0; ks < niter; ks++) {
        __syncthreads();
        if (ks + 1 < niter) stage((ks + 1) & 1, (ks + 1) * 32);
        const bf16_t* Ab = SMEM + (ks & 1) * 4096;
        const bf16_t* Bb = SMEM + 8192 + (ks & 1) * 4096;
        bf16x8 afr[4], bfr[4];
#pragma unroll
        for (int mi = 0; mi < 4; mi++)
            afr[mi] = *(const bf16x8*)(Ab + (size_t)(quad * 128 + mq + mi * 16 + l16) * 8);
#pragma unroll
        for (int ni = 0; ni < 4; ni++)
            bfr[ni] = *(const bf16x8*)(Bb + (size_t)(quad * 128 + nq + ni * 16 + l16) * 8);
#pragma unroll
        for (int mi = 0; mi < 4; mi++)
#pragma unroll
            for (int ni = 0; ni < 4; ni++)
                acc[mi][ni] = __builtin_amdgcn_mfma_f32_16x16x32_bf16(
                    afr[mi], bfr[ni], acc[mi][ni], 0, 0, 0);
    }

    if (OUTBF) {
        __syncthreads();
#pragma unroll
        for (int ni = 0; ni < 4; ni++) {
            int colc = nq + ni * 16 + l16;
            float bv = g.bias ? g.bias[nbase + colc] : 0.f;
            int cc = colc >> 3, off = colc & 7;
#pragma unroll
            for (int mi = 0; mi < 4; mi++)
#pragma unroll
                for (int r = 0; r < 4; r++) {
                    int row = mq + mi * 16 + quad * 4 + r;
                    int sw = (row ^ (row >> 3)) & 7;
                    SMEM[row * 128 + ((cc ^ sw) << 3) + off] =
                        (bf16_t)(acc[mi][ni][r] + bv);
                }
        }
        __syncthreads();
        {
            int row = tid >> 1, seg = tid & 1;
            int sw = (row ^ (row >> 3)) & 7;
            int growr = mbase + row;
            if (growr < M) {
#pragma unroll
                for (int q = 0; q < 8; q++) {
                    int cc = seg * 8 + q;
                    bf16x8 v = *(const bf16x8*)(SMEM + row * 128 + ((cc ^ sw) << 3));
                    *(bf16x8*)(g.Cb + (size_t)growr * ldc + nbase + cc * 8) = v;
                }
            }
        }
    } else {
#pragma unroll
        for (int ni = 0; ni < 4; ni++) {
            int col = nbase + nq + ni * 16 + l16;
            if (col >= N) continue;
            float bv = g.bias ? g.bias[col] : 0.f;
#pragma unroll
            for (int mi = 0; mi < 4; mi++)
#pragma unroll
                for (int r = 0; r < 4; r++) {
                    int row = mbase + mq + mi * 16 + quad * 4 + r;
                    if (row >= M) continue;
                    g.Cf[(size_t)row * ldc + col] = acc[mi][ni][r] + bv;
                }
        }
    }
}

// =======================================================================
// R22: gru_mega (R21 geometry) with acc-init-from-vocGi + direct xin
// epilogue. The r/z MFMA accumulators start at the prefetched vocGi
// values (C-layout matches: col=l16, row=quad*4+r) - drops 48 movs +
// 32 adds per thread per step and 32 VGPR of gi storage. The epilogue
// writes final h1 straight into x_in with the [hn[:B], z, hn[B:]] row
// mapping - assemble_xin launch deleted.
// =======================================================================
struct MegaLay {
    const bf16_t* vocGi;   // [V][768] = temb@Wih0^T + b_ih0
    const int*    gnf;     // [NT][24]
    const bf16_t* whh0;    // frag-major, nks=8
    const bf16_t* wih1;    // frag-major, nks=8
    const bf16_t* whh1;    // frag-major, nks=8
    const float *bhh0, *bih1, *bhh1;
    const bf16_t* h0in;    // [NT][256]
    const bf16_t* h1in;
    bf16_t*       xinout;  // [N][256]: final h1 written at mapped rows
};

__device__ __forceinline__ float rcp_(float x)
{
    float r;
    asm("v_rcp_f32 %0, %1" : "=v"(r) : "v"(x));
    return r;
}
__device__ __forceinline__ float sigm_(float x)
{
    return rcp_(1.f + __expf(-x));
}
__device__ __forceinline__ float tanh_(float x)
{
    x = fminf(fmaxf(x, -15.f), 15.f);
    float t = __expf(2.f * x);
    return 1.f - 2.f * rcp_(t + 1.f);
}

// swizzled LDS addr for h tile [32 rows][512B]: XOR row into byte bits 4-6
#define HSW(Hb, row, byte) ((char*)(Hb) + ((((row) * 512) + (byte)) ^ (((row) & 7) << 4)))

__global__ __launch_bounds__(512, 1) void gru_mega(MegaLay L)
{
    __shared__ __align__(16) bf16_t H0L[8192];    // 16 KB h0[32][256] swizzled
    __shared__ __align__(16) bf16_t H1L[8192];    // 16 KB h1[32][256] swizzled
    __shared__ int TOK[768];                      // 3 KB  tokens [32][24]
    const int tid  = (int)threadIdx.x;
    const int wv   = tid >> 6, lane = tid & 63;   // wv 0..7
    const int quad = lane >> 4, l16 = lane & 15;
    const int row0 = (int)blockIdx.x * 32;

    // ---- tokens + initial h into swizzled LDS ----
    for (int i = tid; i < 768; i += 512) {
        int gi = row0 * T_ + i; if (gi >= NT_ * T_) gi = NT_ * T_ - 1;
        TOK[i] = L.gnf[gi];
    }
#pragma unroll
    for (int i = 0; i < 2; i++) {
        int idx  = i * 512 + tid;
        int rowl = idx >> 5, seg = idx & 31;
        int grow = row0 + rowl; if (grow >= NT_) grow = NT_ - 1;
        *(bf16x8*)HSW(H0L, rowl, seg * 16) =
            *(const bf16x8*)(L.h0in + (size_t)grow * H_ + seg * 8);
        *(bf16x8*)HSW(H1L, rowl, seg * 16) =
            *(const bf16x8*)(L.h1in + (size_t)grow * H_ + seg * 8);
    }

    // per-lane biases for this wave's 32-col slice.
    // L0: Gi carries b_ih0 already -> only bhh0 here. L1: r,z combined.
    float bh0[3][2], brz1[2][2], bni1[2], bnh1[2];
#pragma unroll
    for (int jj = 0; jj < 2; jj++) {
        int col = wv * 32 + jj * 16 + l16;
        bh0[0][jj] = L.bhh0[col];
        bh0[1][jj] = L.bhh0[256 + col];
        bh0[2][jj] = L.bhh0[512 + col];
        brz1[0][jj] = L.bih1[col] + L.bhh1[col];
        brz1[1][jj] = L.bih1[256 + col] + L.bhh1[256 + col];
        bni1[jj]    = L.bih1[512 + col];
        bnh1[jj]    = L.bhh1[512 + col];
    }

    // generic K-loop: A-frags via loader, B-frags frag-major from L2.
    auto run_gemm = [&](auto&& loadA, const bf16_t* W,
                        f32x4 (&arz)[2][2][2], f32x4 (&an)[2][2]) {
#pragma unroll 2
        for (int ks = 0; ks < 8; ks++) {
            bf16x8 bfr[3][2];
#pragma unroll
            for (int g = 0; g < 3; g++)
#pragma unroll
                for (int jj = 0; jj < 2; jj++)
                    bfr[g][jj] = *(const bf16x8*)(W +
                        (((size_t)(g * 16 + wv * 2 + jj) * 8 + ks) << 9) + lane * 8);
            bf16x8 afr[2];
            loadA(afr, ks);
#pragma unroll
            for (int m = 0; m < 2; m++)
#pragma unroll
                for (int jj = 0; jj < 2; jj++) {
                    arz[m][0][jj] = __builtin_amdgcn_mfma_f32_16x16x32_bf16(
                        afr[m], bfr[0][jj], arz[m][0][jj], 0, 0, 0);
                    arz[m][1][jj] = __builtin_amdgcn_mfma_f32_16x16x32_bf16(
                        afr[m], bfr[1][jj], arz[m][1][jj], 0, 0, 0);
                    an[m][jj] = __builtin_amdgcn_mfma_f32_16x16x32_bf16(
                        afr[m], bfr[2][jj], an[m][jj], 0, 0, 0);
                }
        }
    };

    __syncthreads();          // TOK + h visible

    for (int t = 0; t < T_; t++) {
        f32x4 arz[2][2][2], an_i[2][2], an_h[2][2], gin[2][2];

        // ---- prefetch this step's Gi0 (vocGi rows by token) DIRECTLY
        // into the r/z accumulators (C-layout: col=l16, row=quad*4+r);
        // n-gate term kept separate in gin. Loads land during whh0 GEMM.
#pragma unroll
        for (int m = 0; m < 2; m++)
#pragma unroll
            for (int r2 = 0; r2 < 4; r2++) {
                int rowl = m * 16 + quad * 4 + r2;
                const bf16_t* gp = L.vocGi +
                    (size_t)TOK[rowl * T_ + t] * (3 * H_);
#pragma unroll
                for (int jj = 0; jj < 2; jj++) {
                    int col = wv * 32 + jj * 16 + l16;
                    arz[m][0][jj][r2] = (float)gp[col];
                    arz[m][1][jj][r2] = (float)gp[256 + col];
                    gin[m][jj][r2]    = (float)gp[512 + col];
                }
            }
#pragma unroll
        for (int m = 0; m < 2; m++)
#pragma unroll
            for (int jj = 0; jj < 2; jj++)
                an_h[m][jj] = (f32x4){0.f, 0.f, 0.f, 0.f};

        // ---- layer 0: Gh0 = h0 @ Whh0^T accumulated onto Gi0 ----
        run_gemm([&](bf16x8* afr, int ks) {
#pragma unroll
            for (int m = 0; m < 2; m++)
                afr[m] = *(const bf16x8*)HSW(H0L, m * 16 + l16,
                                             ks * 64 + quad * 16);
        }, L.whh0, arz, an_h);
        __syncthreads();      // all h0 reads done

        // ---- gates L0 -> h0 in place ----
#pragma unroll
        for (int m = 0; m < 2; m++)
#pragma unroll
            for (int jj = 0; jj < 2; jj++) {
                int col = wv * 32 + jj * 16 + l16;
#pragma unroll
                for (int r = 0; r < 4; r++) {
                    int rowl = m * 16 + quad * 4 + r;
                    float hold = (float)*(const bf16_t*)HSW(H0L, rowl, col * 2);
                    float rg = sigm_(arz[m][0][jj][r] + bh0[0][jj]);
                    float zg = sigm_(arz[m][1][jj][r] + bh0[1][jj]);
                    float ng = tanh_(gin[m][jj][r] +
                                     rg * (an_h[m][jj][r] + bh0[2][jj]));
                    *(bf16_t*)HSW(H0L, rowl, col * 2) =
                        (bf16_t)((1.f - zg) * ng + zg * hold);
                }
            }
        __syncthreads();      // new h0 visible

        // ---- layer 1: Gi1 (h0 new) + Gh1 (h1) ----
#pragma unroll
        for (int m = 0; m < 2; m++)
#pragma unroll
            for (int jj = 0; jj < 2; jj++) {
                arz[m][0][jj] = (f32x4){0.f, 0.f, 0.f, 0.f};
                arz[m][1][jj] = (f32x4){0.f, 0.f, 0.f, 0.f};
                an_i[m][jj]   = (f32x4){0.f, 0.f, 0.f, 0.f};
                an_h[m][jj]   = (f32x4){0.f, 0.f, 0.f, 0.f};
            }
        run_gemm([&](bf16x8* afr, int ks) {
#pragma unroll
            for (int m = 0; m < 2; m++)
                afr[m] = *(const bf16x8*)HSW(H0L, m * 16 + l16,
                                             ks * 64 + quad * 16);
        }, L.wih1, arz, an_i);
        run_gemm([&](bf16x8* afr, int ks) {
#pragma unroll
            for (int m = 0; m < 2; m++)
                afr[m] = *(const bf16x8*)HSW(H1L, m * 16 + l16,
                                             ks * 64 + quad * 16);
        }, L.whh1, arz, an_h);
        __syncthreads();      // all h0/h1 reads done

        // ---- gates L1 -> h1 in place ----
#pragma unroll
        for (int m = 0; m < 2; m++)
#pragma unroll
            for (int jj = 0; jj < 2; jj++) {
                int col = wv * 32 + jj * 16 + l16;
#pragma unroll
                for (int r = 0; r < 4; r++) {
                    int rowl = m * 16 + quad * 4 + r;
                    float hold = (float)*(const bf16_t*)HSW(H1L, rowl, col * 2);
                    float rg = sigm_(arz[m][0][jj][r] + brz1[0][jj]);
                    float zg = sigm_(arz[m][1][jj][r] + brz1[1][jj]);
                    float ng = tanh_(an_i[m][jj][r] + bni1[jj] +
                                     rg * (an_h[m][jj][r] + bnh1[jj]));
                    *(bf16_t*)HSW(H1L, rowl, col * 2) =
                        (bf16_t)((1.f - zg) * ng + zg * hold);
                }
            }
        // next iteration's first barrier separates these writes from the
        // next step's H1L reads (which occur after two more barriers).
    }

    __syncthreads();
    // ---- epilogue: write final h1 directly into x_in with row mapping
#pragma unroll
    for (int i = 0; i < 2; i++) {
        int idx  = i * 512 + tid;
        int rowl = idx >> 5, seg = idx & 31;
        int grow = row0 + rowl;
        if (grow < NT_) {
            int dst = (grow < B_) ? grow : (grow + NU_);
            bf16x8 v = *(const bf16x8*)HSW(H1L, rowl, seg * 16);
            *(bf16x8*)(L.xinout + (size_t)dst * H_ + seg * 8) = v;
        }
    }
}

// ---------------- prep: all f32->bf16 conversions in one launch ----------------
// transp: 0 = row-major (pad cols), 1 = transpose, 2 = fragment-major
//         (nks = cout/32; cin = src inner dim, zero-pad kk >= cin)
struct SegD { const float* src; bf16_t* dst; int rows, cin, cout, transp; };
struct PrepArgs { SegD seg[11]; long long base[12]; int nseg; long long total; };

__global__ void prep_kern(PrepArgs pa)
{
    long long stride = (long long)gridDim.x * blockDim.x;
    for (long long i = (long long)blockIdx.x * blockDim.x + threadIdx.x;
         i < pa.total; i += stride) {
        int k = 0;
        while (k + 1 < pa.nseg && i >= pa.base[k + 1]) k++;
        long long local = i - pa.base[k];
        SegD sg = pa.seg[k];
        float v;
        if (sg.transp == 2) {
            int nks  = sg.cout >> 5;
            int o    = (int)local;
            int e    = o & 7;
            int lane = (o >> 3) & 63;
            int rest = o >> 9;
            int ks   = rest % nks;
            int gcb  = rest / nks;
            int r    = (gcb >> 4) * 256 + (gcb & 15) * 16 + (lane & 15);
            int kk   = ks * 32 + (lane >> 4) * 8 + e;
            v = (kk < sg.cin) ? sg.src[(size_t)r * sg.cin + kk] : 0.f;
        } else {
            int r = (int)(local / sg.cout);
            int c = (int)(local - (long long)r * sg.cout);
            if (sg.transp) v = sg.src[(size_t)c * sg.rows + r];
            else           v = (c < sg.cin) ? sg.src[(size_t)r * sg.cin + c] : 0.f;
        }
        sg.dst[local] = (bf16_t)v;
    }
}

// ---------------- fused init ----------------
__global__ void init_all(const float* __restrict__ h0in, bf16_t* __restrict__ h0b,
                         bf16_t* __restrict__ h1b,
                         int* __restrict__ deg, int* __restrict__ dcnt,
                         float* __restrict__ loss2, float* __restrict__ b_ml,
                         const float* __restrict__ b_mu, const float* __restrict__ b_lv)
{
    int i = blockIdx.x * blockDim.x + threadIdx.x;
    if (i < NT_ * H_) {
        h0b[i] = (bf16_t)h0in[i];
        h1b[i] = (bf16_t)h0in[NT_ * H_ + i];
    }
    if (i < N_) { deg[i] = 0; dcnt[i] = 0; }
    if (i < 2 * Z_) b_ml[i] = (i < Z_) ? b_mu[i] : b_lv[i - Z_];
    if (i < 2) loss2[i] = 0.f;
}

// ---------------- CSR build (by dst, self-loops appended) ----------------
__device__ __forceinline__ void edge_sd(const int* __restrict__ ei, int e, int& s, int& d)
{
    if (e < E_) { s = ei[e]; d = ei[E_ + e]; }
    else        { s = d = e - E_; }
}

__global__ void csr_hist(const int* __restrict__ ei, int* __restrict__ deg)
{
    int e = blockIdx.x * blockDim.x + threadIdx.x;
    if (e >= E2_) return;
    int s, d; edge_sd(ei, e, s, d);
    atomicAdd(deg + d, 1);
}

__global__ void csr_scan(const int* __restrict__ deg, int* __restrict__ rowptr)
{
    __shared__ int buf[256];
    __shared__ int carry;
    int tid = (int)threadIdx.x;
    if (tid == 0) { carry = 0; rowptr[0] = 0; }
    __syncthreads();
    for (int c0 = 0; c0 < N_; c0 += 256) {
        int i = c0 + tid;
        buf[tid] = (i < N_) ? deg[i] : 0;
        __syncthreads();
        for (int off = 1; off < 256; off <<= 1) {
            int t = (tid >= off) ? buf[tid - off] : 0;
            __syncthreads();
            buf[tid] += t;
            __syncthreads();
        }
        if (i < N_) rowptr[i + 1] = carry + buf[tid];
        __syncthreads();
        if (tid == 255) carry += buf[255];
        __syncthreads();
    }
}

__global__ void csr_scatter(const int* __restrict__ ei, const int* __restrict__ rowptr,
                            int* __restrict__ dcnt, int* __restrict__ csrc)
{
    int e = blockIdx.x * blockDim.x + threadIdx.x;
    if (e >= E2_) return;
    int s, d; edge_sd(ei, e, s, d);
    int pos = rowptr[d] + atomicAdd(dcnt + d, 1);
    csrc[pos] = s;
}

// ---------------- VAE (grid-stride; 256 atomics) ----------------
__global__ __launch_bounds__(256) void vae_z_kl(
    const float* __restrict__ ml, const float* __restrict__ eps,
    bf16_t* __restrict__ z_out, float* __restrict__ kl_out)
{
    float t = 0.f;
    int stride = (int)gridDim.x * 256;
    for (int idx = blockIdx.x * 256 + threadIdx.x; idx < NU_ * Z_; idx += stride) {
        int row = idx >> 8, c = idx & 255;
        float m = ml[(size_t)row * 512 + c];
        float l = ml[(size_t)row * 512 + 256 + c];
        float el = expf(l);
        z_out[idx] = (bf16_t)(m + expf(0.5f * l) * eps[idx]);
        t += -0.5f * (1.f + l - m * m - el);
    }
    __shared__ float red[256];
    red[threadIdx.x] = t;
    __syncthreads();
    for (int s = 128; s > 0; s >>= 1) {
        if ((int)threadIdx.x < s) red[threadIdx.x] += red[threadIdx.x + s];
        __syncthreads();
    }
    if (threadIdx.x == 0) atomicAdd(kl_out, red[0] * (1.f / NU_));
}

__global__ __launch_bounds__(256) void rec_loss_kern(
    const float* __restrict__ rec, const float* __restrict__ uf,
    float* __restrict__ loss_out)
{
    float t = 0.f;
    int stride = (int)gridDim.x * 256;
    for (int idx = blockIdx.x * 256 + threadIdx.x; idx < NU_ * F_; idx += stride) {
        float d = rec[idx] - uf[idx];
        t += d * d;
    }
    __shared__ float red[256];
    red[threadIdx.x] = t;
    __syncthreads();
    for (int s = 128; s > 0; s >>= 1) {
        if ((int)threadIdx.x < s) red[threadIdx.x] += red[threadIdx.x + s];
        __syncthreads();
    }
    if (threadIdx.x == 0) atomicAdd(loss_out, red[0] * (1.f / (NU_ * F_)));
}

// =======================================================================
// R22 GAT: fused inline-coef + single-pass ONLINE-softmax aggregators.
// The old pipeline did {coef kernel (reads all xp rows) -> 2-pass agg
// (reads asn per edge twice + xp once)}. Each agg wave already reads the
// same xp row per edge, so the src logit is computed inline via a 6-step
// __shfl_xor wave reduction, and the softmax is single-pass online
// (running max + rescale, T13 family). Deletes both coef launches, the
// asn/adn arrays, and one full edge pass of scattered reads.
// =======================================================================
// layer 1: BLOCK per dst; wave w handles heads w and w+4; lane = in-head col.
__global__ __launch_bounds__(256) void gat_agg1(
    const int* __restrict__ rowptr, const int* __restrict__ csrc,
    const bf16_t* __restrict__ xp, const float* __restrict__ a_src,
    const float* __restrict__ a_dst, const float* __restrict__ bias,
    bf16_t* __restrict__ x1out)
{
    int d = blockIdx.x;
    int tid = (int)threadIdx.x;
    int w = tid >> 6, lane = tid & 63;
    int h0 = w, h1 = w + 4;
    float as0 = a_src[h0 * 64 + lane], as1 = a_src[h1 * 64 + lane];
    float adv0 = a_dst[h0 * 64 + lane], adv1 = a_dst[h1 * 64 + lane];
    int beg = rowptr[d], end = rowptr[d + 1];

    // dst coefficient (wave reduce over the head's 64 cols)
    float t0 = (float)xp[(size_t)d * 512 + tid] * adv0;
    float t1 = (float)xp[(size_t)d * 512 + 256 + tid] * adv1;
#pragma unroll
    for (int mk = 1; mk < 64; mk <<= 1) {
        t0 += __shfl_xor(t0, mk);
        t1 += __shfl_xor(t1, mk);
    }
    float ad0 = t0, ad1 = t1;

    float m0 = -1e30f, m1 = -1e30f;
    float den0 = 0.f, den1 = 0.f, acc0 = 0.f, acc1 = 0.f;
    for (int e = beg; e < end; e++) {
        int s = csrc[e];
        float x0 = (float)xp[(size_t)s * 512 + tid];
        float x1 = (float)xp[(size_t)s * 512 + 256 + tid];
        float s0 = x0 * as0, s1 = x1 * as1;
#pragma unroll
        for (int mk = 1; mk < 64; mk <<= 1) {
            s0 += __shfl_xor(s0, mk);
            s1 += __shfl_xor(s1, mk);
        }
        float l0 = s0 + ad0; l0 = (l0 > 0.f) ? l0 : 0.2f * l0;
        float l1 = s1 + ad1; l1 = (l1 > 0.f) ? l1 : 0.2f * l1;
        float M0 = fmaxf(m0, l0), sc0 = __expf(m0 - M0), p0 = __expf(l0 - M0);
        den0 = den0 * sc0 + p0; acc0 = acc0 * sc0 + p0 * x0; m0 = M0;
        float M1 = fmaxf(m1, l1), sc1 = __expf(m1 - M1), p1 = __expf(l1 - M1);
        den1 = den1 * sc1 + p1; acc1 = acc1 * sc1 + p1 * x1; m1 = M1;
    }
    x1out[(size_t)d * 512 + tid]       = (bf16_t)(bias[tid] + acc0 / den0);
    x1out[(size_t)d * 512 + 256 + tid] = (bf16_t)(bias[256 + tid] + acc1 / den1);
}

// layer 2 (1 head x 100 ch): wave per dst; lane covers cols lane, 64+lane.
__global__ __launch_bounds__(256) void gat_agg2(
    const int* __restrict__ rowptr, const int* __restrict__ csrc,
    const float* __restrict__ xp, const float* __restrict__ a_src,
    const float* __restrict__ a_dst, const float* __restrict__ bias,
    float* __restrict__ outp)
{
    int d = blockIdx.x * 4 + ((int)threadIdx.x >> 6);
    if (d >= N_) return;
    int lane = (int)threadIdx.x & 63;
    int hi = (lane < H2_ - 64);
    float a0 = a_src[lane], a1 = hi ? a_src[64 + lane] : 0.f;
    float b0 = a_dst[lane], b1 = hi ? a_dst[64 + lane] : 0.f;
    int beg = rowptr[d], end = rowptr[d + 1];

    float xd0 = xp[(size_t)d * H2_ + lane];
    float xd1 = hi ? xp[(size_t)d * H2_ + 64 + lane] : 0.f;
    float t = xd0 * b0 + xd1 * b1;
#pragma unroll
    for (int mk = 1; mk < 64; mk <<= 1) t += __shfl_xor(t, mk);
    float adnd = t;

    float mx = -1e30f, den = 0.f, acc0 = 0.f, acc1 = 0.f;
    for (int e = beg; e < end; e++) {
        int s = csrc[e];
        float x0 = xp[(size_t)s * H2_ + lane];
        float x1 = hi ? xp[(size_t)s * H2_ + 64 + lane] : 0.f;
        float sd = x0 * a0 + x1 * a1;
#pragma unroll
        for (int mk = 1; mk < 64; mk <<= 1) sd += __shfl_xor(sd, mk);
        float l = sd + adnd;
        l = (l > 0.f) ? l : 0.2f * l;
        float M = fmaxf(mx, l), sc = __expf(mx - M), p = __expf(l - M);
        den = den * sc + p;
        acc0 = acc0 * sc + p * x0;
        acc1 = acc1 * sc + p * x1;
        mx = M;
    }
    outp[(size_t)d * H2_ + lane] = bias[lane] + acc0 / den;
    if (hi)
        outp[(size_t)d * H2_ + 64 + lane] = bias[64 + lane] + acc1 / den;
}

// ---------------- launcher ----------------
extern "C" void kernel_launch(void* const* d_in, const int* in_sizes, int n_in,
                              void* d_out, int out_size, void* d_ws, size_t ws_size,
                              hipStream_t stream)
{
    const float* user_feats = (const float*)d_in[1];
    const int*   gnf        = (const int*)d_in[2];
    const int*   ei         = (const int*)d_in[3];
    const float* temb       = (const float*)d_in[4];
    const float* w_ih0      = (const float*)d_in[5];
    const float* w_hh0      = (const float*)d_in[6];
    const float* b_ih0      = (const float*)d_in[7];
    const float* b_hh0      = (const float*)d_in[8];
    const float* w_ih1      = (const float*)d_in[9];
    const float* w_hh1      = (const float*)d_in[10];
    const float* b_ih1      = (const float*)d_in[11];
    const float* b_hh1      = (const float*)d_in[12];
    const float* h0in       = (const float*)d_in[13];
    const float* w_mu       = (const float*)d_in[14];
    const float* b_mu       = (const float*)d_in[15];
    const float* w_lv       = (const float*)d_in[16];
    const float* b_lv       = (const float*)d_in[17];
    const float* w_dec      = (const float*)d_in[18];
    const float* b_dec      = (const float*)d_in[19];
    const float* veps       = (const float*)d_in[20];
    const float* w1         = (const float*)d_in[21];
    const float* a_src1     = (const float*)d_in[22];
    const float* a_dst1     = (const float*)d_in[23];
    const float* b1         = (const float*)d_in[24];
    const float* w2         = (const float*)d_in[25];
    const float* a_src2     = (const float*)d_in[26];
    const float* a_dst2     = (const float*)d_in[27];
    const float* b2         = (const float*)d_in[28];
    float* out = (float*)d_out;

    // ---- workspace (byte offsets) ----
    char* wsb = (char*)d_ws;
    bf16_t* temb_bf = (bf16_t*)(wsb + 0);                 // 19.2 MB
    bf16_t* vocGi   = (bf16_t*)(wsb + 19200000);          // 46.08 MB (ends 65,280,000)
    float*  mlbuf   = (float*)(wsb + 66000000);           // 8.19 MB
    float*  recb    = (float*)(wsb + 75000000);           // 8.19 MB (ends 83,192,000)
    bf16_t* xp1b    = (bf16_t*)(wsb + 0);                 // GAT alias in temb
    bf16_t* x1b     = (bf16_t*)(wsb + 20480000);          // GAT alias in vocGi
    float*  xp2     = (float*)(wsb + 30720000);           // GAT alias in vocGi
    bf16_t* wih0_bf = (bf16_t*)(wsb + 92928000);          // row-major padded [768][320]
    bf16_t* whh0_bf = (bf16_t*)(wsb + 93419520);
    bf16_t* wih1_bf = (bf16_t*)(wsb + 93812736);
    bf16_t* whh1_bf = (bf16_t*)(wsb + 94205952);
    bf16_t* wml_bf  = (bf16_t*)(wsb + 94599168);
    bf16_t* wdec_bf = (bf16_t*)(wsb + 95123456);
    bf16_t* w1t_bf  = (bf16_t*)(wsb + 95385600);
    bf16_t* w2t_bf  = (bf16_t*)(wsb + 95648000);
    float*  b_ml    = (float*)(wsb + 95750400);
    bf16_t* ufeats_bf = (bf16_t*)(wsb + 95752448);
    bf16_t* h0b_init = (bf16_t*)(wsb + 124424448);
    bf16_t* h1init  = (bf16_t*)(wsb + 127496448);
    bf16_t* xin_bf  = (bf16_t*)(wsb + 136712448);
    int*    deg     = (int*)(wsb + 141832448);
    int*    dcnt    = (int*)(wsb + 141872448);
    int*    rowptr  = (int*)(wsb + 141912448);
    int*    csrc    = (int*)(wsb + 141952512);

    const int TB = 256;
    auto blocks = [](int n) { return (n + 255) / 256; };

    auto mkcfg = [](const bf16_t* A, const bf16_t* B, const float* bias,
                    float* Cf, bf16_t* Cb, int M, int N, int K, int ldc,
                    const int* gtok, int t0) {
        GCfg g; g.A = A; g.B = B; g.bias = bias; g.Cf = Cf; g.Cb = Cb;
        g.M = M; g.N = N; g.K = K; g.ldc = ldc; g.gtok = gtok; g.t0 = t0;
        return g;
    };
    auto launch_bf = [&](GCfg g0) {
        dim3 grid((g0.N + 127) / 128, (g0.M + 127) / 128, 1);
        hipLaunchKernelGGL((mfma_gemm<true>), grid, dim3(TB), 0, stream, g0, g0);
    };
    auto launch_f32 = [&](GCfg g0) {
        dim3 grid((g0.N + 127) / 128, (g0.M + 127) / 128, 1);
        hipLaunchKernelGGL((mfma_gemm<false>), grid, dim3(TB), 0, stream, g0, g0);
    };

    // ---- prep ----
    PrepArgs pa;
    auto seg = [&](int k, const float* s, bf16_t* dst, int rows, int cin, int cout, int tr) {
        pa.seg[k] = SegD{s, dst, rows, cin, cout, tr};
    };
    seg(0, temb, temb_bf, V_, D_, DP_, 0);
    seg(1, w_ih0, wih0_bf, 3 * H_, D_, DP_, 0);   // row-major padded (for vocGi GEMM)
    seg(2, w_hh0, whh0_bf, 3 * H_, H_, H_, 2);    // frag-major nks=8
    seg(3, w_ih1, wih1_bf, 3 * H_, H_, H_, 2);    // frag-major nks=8
    seg(4, w_hh1, whh1_bf, 3 * H_, H_, H_, 2);    // frag-major nks=8
    seg(5, w_mu, wml_bf, Z_, F_, F_, 0);
    seg(6, w_lv, wml_bf + (size_t)Z_ * F_, Z_, F_, F_, 0);
    seg(7, w_dec, wdec_bf, F_, Z_, Z_, 0);
    seg(8, user_feats, ufeats_bf, NU_, F_, F_, 0);
    seg(9, w1, w1t_bf, HEADS_ * H1_, 0, H_, 1);
    seg(10, w2, w2t_bf, H2_, 0, HEADS_ * H1_, 1);
    pa.nseg = 11;
    long long acc = 0;
    for (int k = 0; k < 11; k++) {
        pa.base[k] = acc;
        acc += (long long)pa.seg[k].rows * pa.seg[k].cout;
    }
    pa.base[11] = acc;
    pa.total = acc;
    hipLaunchKernelGGL(prep_kern, dim3(6144), dim3(TB), 0, stream, pa);

    hipLaunchKernelGGL(init_all, dim3(blocks(NT_ * H_)), dim3(TB), 0, stream,
                       h0in, h0b_init, h1init,
                       deg, dcnt, out + N_ * H2_, b_ml, b_mu, b_lv);

    // ---- CSR build ----
    hipLaunchKernelGGL(csr_hist, dim3(blocks(E2_)), dim3(TB), 0, stream, ei, deg);
    hipLaunchKernelGGL(csr_scan, dim3(1), dim3(TB), 0, stream, deg, rowptr);
    hipLaunchKernelGGL(csr_scatter, dim3(blocks(E2_)), dim3(TB), 0, stream,
                       ei, rowptr, dcnt, csrc);

    // ---- vocabulary Gi precompute: vocGi = temb @ Wih0^T + b_ih0 ----
    launch_bf(mkcfg(temb_bf, wih0_bf, b_ih0, nullptr, vocGi,
                    V_, 3 * H_, DP_, 3 * H_, nullptr, 0));

    // ---- VAE ----
    launch_f32(mkcfg(ufeats_bf, wml_bf, b_ml, mlbuf, nullptr,
                     NU_, 2 * Z_, F_, 2 * Z_, nullptr, 0));
    bf16_t* z_bf = xin_bf + (size_t)B_ * H_;
    hipLaunchKernelGGL(vae_z_kl, dim3(256), dim3(TB), 0, stream,
                       mlbuf, veps, z_bf, out + N_ * H2_);
    launch_f32(mkcfg(z_bf, wdec_bf, b_dec, recb, nullptr,
                     NU_, F_, Z_, F_, nullptr, 0));
    hipLaunchKernelGGL(rec_loss_kern, dim3(256), dim3(TB), 0, stream,
                       recb, user_feats, out + N_ * H2_ + 1);

    // ---- 2-layer GRU: one fused kernel; writes x_in directly ----
    {
        MegaLay ML;
        ML.vocGi = vocGi; ML.gnf = gnf;
        ML.whh0 = whh0_bf; ML.wih1 = wih1_bf; ML.whh1 = whh1_bf;
        ML.bhh0 = b_hh0; ML.bih1 = b_ih1; ML.bhh1 = b_hh1;
        ML.h0in = h0b_init; ML.h1in = h1init; ML.xinout = xin_bf;
        hipLaunchKernelGGL(gru_mega, dim3((NT_ + 31) / 32), dim3(512), 0, stream, ML);
    }

    // ---- GAT layer 1 (xp1 in bf16; coef fused into agg) ----
    launch_bf(mkcfg(xin_bf, w1t_bf, nullptr, nullptr, xp1b,
                    N_, HEADS_ * H1_, H_, HEADS_ * H1_, nullptr, 0));
    hipLaunchKernelGGL(gat_agg1, dim3(N_), dim3(TB), 0, stream,
                       rowptr, csrc, xp1b, a_src1, a_dst1, b1, x1b);

    // ---- GAT layer 2 (coef fused into agg) ----
    launch_f32(mkcfg(x1b, w2t_bf, nullptr, xp2, nullptr,
                     N_, H2_, HEADS_ * H1_, H2_, nullptr, 0));
    hipLaunchKernelGGL(gat_agg2, dim3((N_ + 3) / 4), dim3(TB), 0, stream,
                       rowptr, csrc, xp2, a_src2, a_dst2, b2, out);

    (void)in_sizes; (void)n_in; (void)out_size; (void)ws_size;
}